// Round 2
// baseline (1459.572 us; speedup 1.0000x reference)
//
#include <hip/hip_runtime.h>
#include <hip/hip_bf16.h>

typedef unsigned short u16;
typedef unsigned int u32;
typedef __bf16 bf16x8 __attribute__((ext_vector_type(8)));
typedef float f32x4 __attribute__((ext_vector_type(4)));
typedef u16 u16x8 __attribute__((ext_vector_type(8)));

#define B_ 2
#define S_ 2048
#define NH 32
#define NKV 8
#define HD 128
#define DIM_ 4096
#define NQKV 6144  // fused projection width: 4096 Q + 1024 K + 1024 V

__device__ inline u16 f2b(float f) {
  u32 u = __builtin_bit_cast(u32, f);
  u = (u + 0x7fffu + ((u >> 16) & 1u)) >> 16;
  return (u16)u;
}
__device__ inline float b2f(u16 b) {
  u32 u = ((u32)b) << 16;
  return __builtin_bit_cast(float, u);
}

__device__ inline void gload_lds16(const u16* g, u16* l) {
  __builtin_amdgcn_global_load_lds((__attribute__((address_space(1))) void*)g,
                                   (__attribute__((address_space(3))) void*)l, 16, 0, 0);
}

// ---------------- f32 -> bf16 cast ----------------
__global__ __launch_bounds__(256) void k_f32_to_bf16(const float* __restrict__ in,
                                                     u16* __restrict__ out, int n4) {
  int i = blockIdx.x * 256 + threadIdx.x;
  if (i >= n4) return;
  const float4 v = ((const float4*)in)[i];
  u32 lo = (u32)f2b(v.x) | ((u32)f2b(v.y) << 16);
  u32 hi = (u32)f2b(v.z) | ((u32)f2b(v.w) << 16);
  ((u32*)out)[(size_t)i * 2] = lo;
  ((u32*)out)[(size_t)i * 2 + 1] = hi;
}

// ---------------- GEMM: C[M][N] = A[M][K] * B[N][K]^T, bf16 in, f32 acc ----------------
// m97 structure: linear LDS [128][64], global_load_lds width-16 staging.
template <int OUTF32>
__global__ __launch_bounds__(256) void k_gemm_bt(const u16* __restrict__ A,
                                                 const u16* __restrict__ Bm,
                                                 void* __restrict__ Cout,
                                                 int M, int N, int K) {
  constexpr int BK = 64;
  __shared__ u16 As[128 * BK];
  __shared__ u16 Bs[128 * BK];
  const int tid = threadIdx.x;
  const int lane = tid & 63, wid = tid >> 6;
  const int wr = wid >> 1, wc = wid & 1;
  const int lr = lane & 15, lg = lane >> 4;
  const int m0 = blockIdx.x * 128, n0 = blockIdx.y * 128;
  f32x4 acc[4][4] = {};
  const int srow = tid >> 3, scol = (tid & 7) * 8;  // matches lds flat = tid*8 u16
  const u16* ap = A + (size_t)(m0 + srow) * K + scol;
  const u16* bp = Bm + (size_t)(n0 + srow) * K + scol;
  for (int k0 = 0; k0 < K; k0 += BK) {
#pragma unroll
    for (int i = 0; i < 4; ++i) {
      gload_lds16(ap + (size_t)(32 * i) * K + k0, &As[i * 2048 + wid * 512]);
      gload_lds16(bp + (size_t)(32 * i) * K + k0, &Bs[i * 2048 + wid * 512]);
    }
    __syncthreads();  // drains vmcnt
#pragma unroll
    for (int ks = 0; ks < 2; ++ks) {
      bf16x8 af[4], bfr[4];
#pragma unroll
      for (int mi = 0; mi < 4; ++mi)
        af[mi] = *(const bf16x8*)&As[(wr * 64 + mi * 16 + lr) * BK + ks * 32 + lg * 8];
#pragma unroll
      for (int ni = 0; ni < 4; ++ni)
        bfr[ni] = *(const bf16x8*)&Bs[(wc * 64 + ni * 16 + lr) * BK + ks * 32 + lg * 8];
#pragma unroll
      for (int mi = 0; mi < 4; ++mi)
#pragma unroll
        for (int ni = 0; ni < 4; ++ni)
          acc[mi][ni] = __builtin_amdgcn_mfma_f32_16x16x32_bf16(af[mi], bfr[ni], acc[mi][ni], 0, 0, 0);
    }
    __syncthreads();
  }
  // D layout: col = lane&15, row = (lane>>4)*4 + j  [m89/m91]
#pragma unroll
  for (int mi = 0; mi < 4; ++mi) {
    const int r = m0 + wr * 64 + mi * 16 + lg * 4;
#pragma unroll
    for (int ni = 0; ni < 4; ++ni) {
      const int cc = n0 + wc * 64 + ni * 16 + lr;
#pragma unroll
      for (int j = 0; j < 4; ++j) {
        float v = acc[mi][ni][j];
        if (OUTF32)
          ((float*)Cout)[(size_t)(r + j) * N + cc] = v;
        else
          ((u16*)Cout)[(size_t)(r + j) * N + cc] = f2b(v);
      }
    }
  }
}

// ---------------- RoPE + permute [B][S][RS-cols] -> [B][H][S][D] ----------------
__global__ __launch_bounds__(256) void k_rope_perm(const u16* __restrict__ src,
                                                   u16* __restrict__ dst,
                                                   const float* __restrict__ cosb,
                                                   const float* __restrict__ sinb, int H,
                                                   int rs, int coloff) {
  const int row = blockIdx.x * 4 + (threadIdx.x >> 6);  // row = (b*H + h)*S + s
  const int lane = threadIdx.x & 63;
  const int s = row & (S_ - 1);
  const int h = (row >> 11) % H;
  const int b = row / (S_ * H);
  const u16* sp = src + ((size_t)b * S_ + s) * rs + coloff + h * HD + lane * 2;
  const u32 u = *(const u32*)sp;
  const float f0 = b2f((u16)(u & 0xffffu));
  const float f1 = b2f((u16)(u >> 16));
  const float c = cosb[s * 64 + lane];
  const float sn = sinb[s * 64 + lane];
  const float r0 = f0 * c - f1 * sn;
  const float r1 = f0 * sn + f1 * c;
  const u32 o = (u32)f2b(r0) | ((u32)f2b(r1) << 16);
  *(u32*)(dst + (size_t)row * HD + lane * 2) = o;
}

// ---------------- V transpose: [B][S][rs cols @coloff] -> [B][NKV][HD][S] ----------------
__global__ __launch_bounds__(256) void k_transpose_v(const u16* __restrict__ vp,
                                                     u16* __restrict__ vt, int rs, int coloff) {
  __shared__ u16 tile[64][72];
  const int s0 = blockIdx.x * 64, d0 = blockIdx.y * 64;
  const int b = blockIdx.z >> 3, kvh = blockIdx.z & 7;
  const int tid = threadIdx.x;
  const int r = tid >> 3, c8 = (tid & 7) * 8;
#pragma unroll
  for (int i = 0; i < 2; ++i) {
    const int sl = r + 32 * i;
    *(u16x8*)&tile[sl][c8] =
        *(const u16x8*)&vp[((size_t)b * S_ + s0 + sl) * rs + coloff + kvh * HD + d0 + c8];
  }
  __syncthreads();
#pragma unroll
  for (int i = 0; i < 2; ++i) {
    const int dl = r + 32 * i;
    u16x8 o;
#pragma unroll
    for (int j = 0; j < 8; ++j) o[j] = tile[c8 + j][dl];
    *(u16x8*)&vt[(((size_t)b * NKV + kvh) * HD + d0 + dl) * S_ + s0 + c8] = o;
  }
}

// ---------------- Flash attention, causal, GQA rep=4, no-LDS-staging ----------------
// Q: [B][NH][S][HD], K: [B][NKV][S][HD], Vt: [B][NKV][HD][S], O: [B][S][NH*HD]
// K/V are L2-resident (512KB per (b,kvh)); fragments read straight from global.
__global__ __launch_bounds__(256) void k_attn(const u16* __restrict__ Qg,
                                              const u16* __restrict__ Kg,
                                              const u16* __restrict__ Vtg,
                                              u16* __restrict__ Og) {
  constexpr int QB = 64, KB = 64;
  __shared__ u16 Ps[4][16][KB + 8];  // per-wave private P
  const int qt = (int)gridDim.x - 1 - (int)blockIdx.x;  // longest blocks first
  const int h = blockIdx.y, b = blockIdx.z;
  const int kvh = h >> 2;
  const int tid = threadIdx.x, wid = tid >> 6, lane = tid & 63;
  const int lr = lane & 15, lg = lane >> 4;
  const int q0 = qt * QB;
  const u16* qp = Qg + (((size_t)b * NH + h) * S_ + q0 + wid * 16 + lr) * HD + lg * 8;
  bf16x8 qf[4];
#pragma unroll
  for (int ks = 0; ks < 4; ++ks) qf[ks] = *(const bf16x8*)(qp + ks * 32);
  f32x4 o[8] = {};
  float mrun[4], lrun[4];
#pragma unroll
  for (int j = 0; j < 4; ++j) { mrun[j] = -1e30f; lrun[j] = 0.f; }
  const u16* kb = Kg + ((size_t)b * NKV + kvh) * (size_t)S_ * HD + (size_t)lr * HD + lg * 8;
  const u16* vb = Vtg + ((size_t)b * NKV + kvh) * (size_t)HD * S_ + (size_t)lr * S_ + lg * 8;
  for (int t = 0; t <= qt; ++t) {
    // K fragments direct from global (L2)
    bf16x8 kf[4][4];
#pragma unroll
    for (int n = 0; n < 4; ++n)
#pragma unroll
      for (int ks = 0; ks < 4; ++ks)
        kf[ks][n] = *(const bf16x8*)(kb + (size_t)(t * KB + n * 16) * HD + ks * 32);
    f32x4 s[4] = {};
#pragma unroll
    for (int ks = 0; ks < 4; ++ks)
#pragma unroll
      for (int n = 0; n < 4; ++n)
        s[n] = __builtin_amdgcn_mfma_f32_16x16x32_bf16(qf[ks], kf[ks][n], s[n], 0, 0, 0);
    const float scale = 0.08838834764831845f;
    float sv[4][4], pm[4];
#pragma unroll
    for (int j = 0; j < 4; ++j) pm[j] = -1e30f;
    const bool diag = (t == qt);
#pragma unroll
    for (int n = 0; n < 4; ++n)
#pragma unroll
      for (int j = 0; j < 4; ++j) {
        float v = s[n][j] * scale;
        if (diag && (n * 16 + lr > wid * 16 + lg * 4 + j)) v = -1e30f;  // causal
        sv[n][j] = v;
        pm[j] = fmaxf(pm[j], v);
      }
#pragma unroll
    for (int off = 1; off < 16; off <<= 1)
#pragma unroll
      for (int j = 0; j < 4; ++j) pm[j] = fmaxf(pm[j], __shfl_xor(pm[j], off));
    float al[4];
#pragma unroll
    for (int j = 0; j < 4; ++j) {
      const float mt = fmaxf(mrun[j], pm[j]);
      al[j] = __expf(mrun[j] - mt);
      mrun[j] = mt;
    }
    float ls[4] = {0.f, 0.f, 0.f, 0.f};
#pragma unroll
    for (int n = 0; n < 4; ++n)
#pragma unroll
      for (int j = 0; j < 4; ++j) {
        const float p = __expf(sv[n][j] - mrun[j]);
        ls[j] += p;
        Ps[wid][lg * 4 + j][n * 16 + lr] = f2b(p);
      }
#pragma unroll
    for (int off = 1; off < 16; off <<= 1)
#pragma unroll
      for (int j = 0; j < 4; ++j) ls[j] += __shfl_xor(ls[j], off);
#pragma unroll
    for (int j = 0; j < 4; ++j) lrun[j] = lrun[j] * al[j] + ls[j];
#pragma unroll
    for (int c = 0; c < 8; ++c)
#pragma unroll
      for (int j = 0; j < 4; ++j) o[c][j] *= al[j];
    // wave-private LDS RAW: ensure P writes complete before fragment reads
    asm volatile("s_waitcnt lgkmcnt(0)" ::: "memory");
    // O += P V   (16x128 per wave); V^T fragments direct from global (L2)
#pragma unroll
    for (int ks = 0; ks < 2; ++ks) {
      bf16x8 af = *(const bf16x8*)&Ps[wid][lr][ks * 32 + lg * 8];
#pragma unroll
      for (int c = 0; c < 8; ++c) {
        bf16x8 vf = *(const bf16x8*)(vb + (size_t)(c * 16) * S_ + t * KB + ks * 32);
        o[c] = __builtin_amdgcn_mfma_f32_16x16x32_bf16(af, vf, o[c], 0, 0, 0);
      }
    }
  }
#pragma unroll
  for (int c = 0; c < 8; ++c)
#pragma unroll
    for (int j = 0; j < 4; ++j) {
      const int srow = q0 + wid * 16 + lg * 4 + j;
      const float v = o[c][j] / lrun[j];
      Og[((size_t)b * S_ + srow) * (NH * HD) + h * HD + c * 16 + lr] = f2b(v);
    }
}

extern "C" void kernel_launch(void* const* d_in, const int* in_sizes, int n_in,
                              void* d_out, int out_size, void* d_ws, size_t ws_size,
                              hipStream_t stream) {
  const float* x = (const float*)d_in[0];
  const float* fc = (const float*)d_in[1];
  const float* fs = (const float*)d_in[2];
  // d_in[3] positions (identity), d_in[4] mask (pure causal: WINDOW>=SEQ) -- analytic
  const float* wq = (const float*)d_in[5];
  const float* wk = (const float*)d_in[6];
  const float* wv = (const float*)d_in[7];
  const float* wo = (const float*)d_in[8];
  char* ws = (char*)d_ws;
  const size_t MB = 1024 * 1024;
  u16* xb = (u16*)(ws);                  // 32 MB  [4096][4096]
  u16* wqkvb = (u16*)(ws + 32 * MB);     // 48 MB  [6144][4096]: wq rows 0-4095, wk 4096-5119, wv 5120-6143
  u16* wkb = wqkvb + (size_t)4096 * 4096;
  u16* wvb = wqkvb + (size_t)5120 * 4096;
  u16* wob = (u16*)(ws + 80 * MB);       // 32 MB
  u16* qkvp = (u16*)(ws + 112 * MB);     // 48 MB  [B*S=4096][6144]
  // liveness reuse:
  u16* Q = xb;                           // [B][NH][S][HD] 32 MB (xb free after qkv gemm)
  u16* Kr = (u16*)(ws + 32 * MB);        // 8 MB (weights free after gemm)
  u16* Vt = (u16*)(ws + 40 * MB);        // 8 MB
  u16* attn = (u16*)(ws + 48 * MB);      // 32 MB
  float* out = (float*)d_out;

  k_f32_to_bf16<<<16384, 256, 0, stream>>>(x, xb, 4194304);
  k_f32_to_bf16<<<16384, 256, 0, stream>>>(wq, wqkvb, 4194304);
  k_f32_to_bf16<<<4096, 256, 0, stream>>>(wk, wkb, 1048576);
  k_f32_to_bf16<<<4096, 256, 0, stream>>>(wv, wvb, 1048576);
  k_f32_to_bf16<<<16384, 256, 0, stream>>>(wo, wob, 4194304);

  // fused QKV projection: [4096][4096] x [6144][4096]^T -> [4096][6144]
  k_gemm_bt<0><<<dim3(32, 48), 256, 0, stream>>>(xb, wqkvb, qkvp, 4096, NQKV, 4096);

  k_rope_perm<<<32768, 256, 0, stream>>>(qkvp, Q, fc, fs, NH, NQKV, 0);
  k_rope_perm<<<8192, 256, 0, stream>>>(qkvp, Kr, fc, fs, NKV, NQKV, 4096);
  k_transpose_v<<<dim3(32, 2, 16), 256, 0, stream>>>(qkvp, Vt, NQKV, 5120);

  k_attn<<<dim3(32, 32, 2), 256, 0, stream>>>(Q, Kr, Vt, attn);

  k_gemm_bt<1><<<dim3(32, 32), 256, 0, stream>>>(attn, wob, out, 4096, 4096, 4096);
}

// Round 3
// 751.970 us; speedup vs baseline: 1.9410x; 1.9410x over previous
//
#include <hip/hip_runtime.h>
#include <hip/hip_bf16.h>

typedef unsigned short u16;
typedef unsigned int u32;
typedef __bf16 bf16x8 __attribute__((ext_vector_type(8)));
typedef float f32x4 __attribute__((ext_vector_type(4)));
typedef u16 u16x8 __attribute__((ext_vector_type(8)));

#define B_ 2
#define S_ 2048
#define NH 32
#define NKV 8
#define HD 128
#define DIM_ 4096
#define NQKV 6144  // fused projection width: 4096 Q + 1024 K + 1024 V

__device__ inline u16 f2b(float f) {
  u32 u = __builtin_bit_cast(u32, f);
  u = (u + 0x7fffu + ((u >> 16) & 1u)) >> 16;
  return (u16)u;
}
__device__ inline float b2f(u16 b) {
  u32 u = ((u32)b) << 16;
  return __builtin_bit_cast(float, u);
}

__device__ inline void gload_lds16(const u16* g, u16* l) {
  __builtin_amdgcn_global_load_lds((__attribute__((address_space(1))) void*)g,
                                   (__attribute__((address_space(3))) void*)l, 16, 0, 0);
}

// ---------------- f32 -> bf16 cast ----------------
__global__ __launch_bounds__(256) void k_f32_to_bf16(const float* __restrict__ in,
                                                     u16* __restrict__ out, int n4) {
  int i = blockIdx.x * 256 + threadIdx.x;
  if (i >= n4) return;
  const float4 v = ((const float4*)in)[i];
  u32 lo = (u32)f2b(v.x) | ((u32)f2b(v.y) << 16);
  u32 hi = (u32)f2b(v.z) | ((u32)f2b(v.w) << 16);
  ((u32*)out)[(size_t)i * 2] = lo;
  ((u32*)out)[(size_t)i * 2 + 1] = hi;
}

// ---------------- GEMM: C[M][N] = A[M][K] * B[N][K]^T, bf16 in, f32 acc ----------------
template <int OUTF32>
__global__ __launch_bounds__(256) void k_gemm_bt(const u16* __restrict__ A,
                                                 const u16* __restrict__ Bm,
                                                 void* __restrict__ Cout,
                                                 int M, int N, int K) {
  constexpr int BK = 64;
  __shared__ __align__(16) u16 As[128 * BK];
  __shared__ __align__(16) u16 Bs[128 * BK];
  const int tid = threadIdx.x;
  const int lane = tid & 63, wid = tid >> 6;
  const int wr = wid >> 1, wc = wid & 1;
  const int lr = lane & 15, lg = lane >> 4;
  const int m0 = blockIdx.x * 128, n0 = blockIdx.y * 128;
  f32x4 acc[4][4] = {};
  const int srow = tid >> 3, scol = (tid & 7) * 8;
  const u16* ap = A + (size_t)(m0 + srow) * K + scol;
  const u16* bp = Bm + (size_t)(n0 + srow) * K + scol;
  for (int k0 = 0; k0 < K; k0 += BK) {
#pragma unroll
    for (int i = 0; i < 4; ++i) {
      gload_lds16(ap + (size_t)(32 * i) * K + k0, &As[i * 2048 + wid * 512]);
      gload_lds16(bp + (size_t)(32 * i) * K + k0, &Bs[i * 2048 + wid * 512]);
    }
    __syncthreads();
#pragma unroll
    for (int ks = 0; ks < 2; ++ks) {
      bf16x8 af[4], bfr[4];
#pragma unroll
      for (int mi = 0; mi < 4; ++mi)
        af[mi] = *(const bf16x8*)&As[(wr * 64 + mi * 16 + lr) * BK + ks * 32 + lg * 8];
#pragma unroll
      for (int ni = 0; ni < 4; ++ni)
        bfr[ni] = *(const bf16x8*)&Bs[(wc * 64 + ni * 16 + lr) * BK + ks * 32 + lg * 8];
#pragma unroll
      for (int mi = 0; mi < 4; ++mi)
#pragma unroll
        for (int ni = 0; ni < 4; ++ni)
          acc[mi][ni] = __builtin_amdgcn_mfma_f32_16x16x32_bf16(af[mi], bfr[ni], acc[mi][ni], 0, 0, 0);
    }
    __syncthreads();
  }
#pragma unroll
  for (int mi = 0; mi < 4; ++mi) {
    const int r = m0 + wr * 64 + mi * 16 + lg * 4;
#pragma unroll
    for (int ni = 0; ni < 4; ++ni) {
      const int cc = n0 + wc * 64 + ni * 16 + lr;
#pragma unroll
      for (int j = 0; j < 4; ++j) {
        float v = acc[mi][ni][j];
        if (OUTF32)
          ((float*)Cout)[(size_t)(r + j) * N + cc] = v;
        else
          ((u16*)Cout)[(size_t)(r + j) * N + cc] = f2b(v);
      }
    }
  }
}

// ---------------- RoPE + permute [B][S][RS-cols] -> [B][H][S][D] ----------------
__global__ __launch_bounds__(256) void k_rope_perm(const u16* __restrict__ src,
                                                   u16* __restrict__ dst,
                                                   const float* __restrict__ cosb,
                                                   const float* __restrict__ sinb, int H,
                                                   int rs, int coloff) {
  const int row = blockIdx.x * 4 + (threadIdx.x >> 6);
  const int lane = threadIdx.x & 63;
  const int s = row & (S_ - 1);
  const int h = (row >> 11) % H;
  const int b = row / (S_ * H);
  const u16* sp = src + ((size_t)b * S_ + s) * rs + coloff + h * HD + lane * 2;
  const u32 u = *(const u32*)sp;
  const float f0 = b2f((u16)(u & 0xffffu));
  const float f1 = b2f((u16)(u >> 16));
  const float c = cosb[s * 64 + lane];
  const float sn = sinb[s * 64 + lane];
  const float r0 = f0 * c - f1 * sn;
  const float r1 = f0 * sn + f1 * c;
  const u32 o = (u32)f2b(r0) | ((u32)f2b(r1) << 16);
  *(u32*)(dst + (size_t)row * HD + lane * 2) = o;
}

// ---------------- V transpose: [B][S][rs cols @coloff] -> [B][NKV][HD][S] ----------------
__global__ __launch_bounds__(256) void k_transpose_v(const u16* __restrict__ vp,
                                                     u16* __restrict__ vt, int rs, int coloff) {
  __shared__ u16 tile[64][72];
  const int s0 = blockIdx.x * 64, d0 = blockIdx.y * 64;
  const int b = blockIdx.z >> 3, kvh = blockIdx.z & 7;
  const int tid = threadIdx.x;
  const int r = tid >> 3, c8 = (tid & 7) * 8;
#pragma unroll
  for (int i = 0; i < 2; ++i) {
    const int sl = r + 32 * i;
    *(u16x8*)&tile[sl][c8] =
        *(const u16x8*)&vp[((size_t)b * S_ + s0 + sl) * rs + coloff + kvh * HD + d0 + c8];
  }
  __syncthreads();
#pragma unroll
  for (int i = 0; i < 2; ++i) {
    const int dl = r + 32 * i;
    u16x8 o;
#pragma unroll
    for (int j = 0; j < 8; ++j) o[j] = tile[c8 + j][dl];
    *(u16x8*)&vt[(((size_t)b * NKV + kvh) * HD + d0 + dl) * S_ + s0 + c8] = o;
  }
}

// ---------------- Flash attention, causal, GQA rep=4 ----------------
// XCD-aware decode: each XCD owns 2 (b,kvh) groups -> K+V working set 2MB, L2-resident.
// Double-buffered async LDS staging (global_load_lds, linear dest, pre-swizzled source).
// Q: [B][NH][S][HD], K: [B][NKV][S][HD], Vt: [B][NKV][HD][S], O: [B][S][NH*HD]
__global__ __launch_bounds__(256) void k_attn(const u16* __restrict__ Qg,
                                              const u16* __restrict__ Kg,
                                              const u16* __restrict__ Vtg,
                                              u16* __restrict__ Og) {
  constexpr int QB = 64, KB = 64;
  __shared__ __align__(16) u16 Ks[2][KB * HD];   // 2 x 16KB, rows 256B, XOR-swizzled
  __shared__ __align__(16) u16 Vs[2][HD * KB];   // 2 x 16KB, rows 128B, XOR-swizzled
  __shared__ u16 Ps[4][16][KB + 8];              // per-wave private P
  // --- XCD-locality block decode ---
  const int bid = blockIdx.x;
  const int xcd = bid & 7, slot = bid >> 3;
  const int g = xcd * 2 + (slot >> 7);    // (b,kvh) group 0..15
  const int r_ = slot & 127;
  const int hq = r_ & 3;
  const int qt = 31 - (r_ >> 2);          // longest blocks first
  const int b = g >> 3, kvh = g & 7, h = kvh * 4 + hq;
  const int tid = threadIdx.x, wid = tid >> 6, lane = tid & 63;
  const int lr = lane & 15, lg = lane >> 4;
  const int q0 = qt * QB;
  const u16* qp = Qg + (((size_t)b * NH + h) * S_ + q0 + wid * 16 + lr) * HD + lg * 8;
  bf16x8 qf[4];
#pragma unroll
  for (int ks = 0; ks < 4; ++ks) qf[ks] = *(const bf16x8*)(qp + ks * 32);
  f32x4 o[8] = {};
  float mrun[4], lrun[4];
#pragma unroll
  for (int j = 0; j < 4; ++j) { mrun[j] = -1e30f; lrun[j] = 0.f; }
  const u16* kb2 = Kg + ((size_t)b * NKV + kvh) * (size_t)S_ * HD;
  const u16* vb2 = Vtg + ((size_t)b * NKV + kvh) * (size_t)HD * S_;

  // Stage tile T into buffer BUF. LDS dest linear (wave-uniform base + lane*16);
  // global source pre-swizzled with byte ^= ((row&7)<<4) so LDS reads can de-swizzle.
#define STAGE_KV(BUF, T)                                                              \
  {                                                                                   \
    _Pragma("unroll") for (int i = 0; i < 4; ++i) {                                   \
      const int kr = wid * 16 + i * 4 + (lane >> 4);                                  \
      gload_lds16(kb2 + (size_t)((T) * KB + kr) * HD + ((lane & 15) ^ (kr & 7)) * 8,  \
                  &Ks[BUF][(wid * 16 + i * 4) * HD]);                                 \
    }                                                                                 \
    _Pragma("unroll") for (int i = 0; i < 4; ++i) {                                   \
      const int dr = wid * 32 + i * 8 + (lane >> 3);                                  \
      gload_lds16(vb2 + (size_t)dr * S_ + (T) * KB + ((lane & 7) ^ (dr & 7)) * 8,     \
                  &Vs[BUF][(wid * 32 + i * 8) * KB]);                                 \
    }                                                                                 \
  }

  STAGE_KV(0, 0);
  asm volatile("s_waitcnt vmcnt(0)" ::: "memory");
  __builtin_amdgcn_sched_barrier(0);
  __builtin_amdgcn_s_barrier();
  __builtin_amdgcn_sched_barrier(0);
  int cur = 0;
  for (int t = 0; t <= qt; ++t) {
    if (t < qt) STAGE_KV(cur ^ 1, t + 1);
    __builtin_amdgcn_sched_barrier(0);
    const char* KsB = (const char*)&Ks[cur][0];
    const char* VsB = (const char*)&Vs[cur][0];
    // S = Q K^T  (16x64 per wave)
    f32x4 s[4] = {};
#pragma unroll
    for (int ks = 0; ks < 4; ++ks) {
      bf16x8 kf4[4];
#pragma unroll
      for (int n = 0; n < 4; ++n) {
        const int rr = n * 16 + lr;
        kf4[n] = *(const bf16x8*)(KsB + rr * 256 + ((ks * 64 + lg * 16) ^ ((rr & 7) << 4)));
      }
#pragma unroll
      for (int n = 0; n < 4; ++n)
        s[n] = __builtin_amdgcn_mfma_f32_16x16x32_bf16(qf[ks], kf4[n], s[n], 0, 0, 0);
    }
    const float scale = 0.08838834764831845f;
    float sv[4][4], pm[4];
#pragma unroll
    for (int j = 0; j < 4; ++j) pm[j] = -1e30f;
    const bool diag = (t == qt);
#pragma unroll
    for (int n = 0; n < 4; ++n)
#pragma unroll
      for (int j = 0; j < 4; ++j) {
        float v = s[n][j] * scale;
        if (diag && (n * 16 + lr > wid * 16 + lg * 4 + j)) v = -1e30f;  // causal
        sv[n][j] = v;
        pm[j] = fmaxf(pm[j], v);
      }
#pragma unroll
    for (int off = 1; off < 16; off <<= 1)
#pragma unroll
      for (int j = 0; j < 4; ++j) pm[j] = fmaxf(pm[j], __shfl_xor(pm[j], off));
    float al[4];
#pragma unroll
    for (int j = 0; j < 4; ++j) {
      const float mt = fmaxf(mrun[j], pm[j]);
      al[j] = __expf(mrun[j] - mt);
      mrun[j] = mt;
    }
    float ls[4] = {0.f, 0.f, 0.f, 0.f};
#pragma unroll
    for (int n = 0; n < 4; ++n)
#pragma unroll
      for (int j = 0; j < 4; ++j) {
        const float p = __expf(sv[n][j] - mrun[j]);
        ls[j] += p;
        Ps[wid][lg * 4 + j][n * 16 + lr] = f2b(p);
      }
#pragma unroll
    for (int off = 1; off < 16; off <<= 1)
#pragma unroll
      for (int j = 0; j < 4; ++j) ls[j] += __shfl_xor(ls[j], off);
#pragma unroll
    for (int j = 0; j < 4; ++j) lrun[j] = lrun[j] * al[j] + ls[j];
#pragma unroll
    for (int c = 0; c < 8; ++c)
#pragma unroll
      for (int j = 0; j < 4; ++j) o[c][j] *= al[j];
    // wave-private LDS RAW: P writes must land before fragment reads
    asm volatile("s_waitcnt lgkmcnt(0)" ::: "memory");
    __builtin_amdgcn_sched_barrier(0);
    // O += P V   (16x128 per wave)
#pragma unroll
    for (int ks = 0; ks < 2; ++ks) {
      bf16x8 af = *(const bf16x8*)&Ps[wid][lr][ks * 32 + lg * 8];
#pragma unroll
      for (int c = 0; c < 8; ++c) {
        const int rv = c * 16 + lr;
        bf16x8 vf = *(const bf16x8*)(VsB + rv * 128 + ((ks * 64 + lg * 16) ^ ((rv & 7) << 4)));
        o[c] = __builtin_amdgcn_mfma_f32_16x16x32_bf16(af, vf, o[c], 0, 0, 0);
      }
    }
    // end of tile: drain next-tile staging loads, then barrier (counted-wait 2-phase)
    asm volatile("s_waitcnt vmcnt(0)" ::: "memory");
    __builtin_amdgcn_sched_barrier(0);
    __builtin_amdgcn_s_barrier();
    __builtin_amdgcn_sched_barrier(0);
    cur ^= 1;
  }
#undef STAGE_KV
#pragma unroll
  for (int c = 0; c < 8; ++c)
#pragma unroll
    for (int j = 0; j < 4; ++j) {
      const int srow = q0 + wid * 16 + lg * 4 + j;
      const float v = o[c][j] / lrun[j];
      Og[((size_t)b * S_ + srow) * (NH * HD) + h * HD + c * 16 + lr] = f2b(v);
    }
}

extern "C" void kernel_launch(void* const* d_in, const int* in_sizes, int n_in,
                              void* d_out, int out_size, void* d_ws, size_t ws_size,
                              hipStream_t stream) {
  const float* x = (const float*)d_in[0];
  const float* fc = (const float*)d_in[1];
  const float* fs = (const float*)d_in[2];
  // d_in[3] positions (identity), d_in[4] mask (pure causal: WINDOW>=SEQ) -- analytic
  const float* wq = (const float*)d_in[5];
  const float* wk = (const float*)d_in[6];
  const float* wv = (const float*)d_in[7];
  const float* wo = (const float*)d_in[8];
  char* ws = (char*)d_ws;
  const size_t MB = 1024 * 1024;
  u16* xb = (u16*)(ws);                  // 32 MB  [4096][4096]
  u16* wqkvb = (u16*)(ws + 32 * MB);     // 48 MB  [6144][4096]
  u16* wkb = wqkvb + (size_t)4096 * 4096;
  u16* wvb = wqkvb + (size_t)5120 * 4096;
  u16* wob = (u16*)(ws + 80 * MB);       // 32 MB
  u16* qkvp = (u16*)(ws + 112 * MB);     // 48 MB  [B*S=4096][6144]
  // liveness reuse:
  u16* Q = xb;                           // [B][NH][S][HD] (xb free after qkv gemm)
  u16* Kr = (u16*)(ws + 32 * MB);        // 8 MB
  u16* Vt = (u16*)(ws + 40 * MB);        // 8 MB
  u16* attn = (u16*)(ws + 48 * MB);      // 32 MB
  float* out = (float*)d_out;

  k_f32_to_bf16<<<16384, 256, 0, stream>>>(x, xb, 4194304);
  k_f32_to_bf16<<<16384, 256, 0, stream>>>(wq, wqkvb, 4194304);
  k_f32_to_bf16<<<4096, 256, 0, stream>>>(wk, wkb, 1048576);
  k_f32_to_bf16<<<4096, 256, 0, stream>>>(wv, wvb, 1048576);
  k_f32_to_bf16<<<16384, 256, 0, stream>>>(wo, wob, 4194304);

  // fused QKV projection: [4096][4096] x [6144][4096]^T -> [4096][6144]
  k_gemm_bt<0><<<dim3(32, 48), 256, 0, stream>>>(xb, wqkvb, qkvp, 4096, NQKV, 4096);

  k_rope_perm<<<32768, 256, 0, stream>>>(qkvp, Q, fc, fs, NH, NQKV, 0);
  k_rope_perm<<<8192, 256, 0, stream>>>(qkvp, Kr, fc, fs, NKV, NQKV, 4096);
  k_transpose_v<<<dim3(32, 2, 16), 256, 0, stream>>>(qkvp, Vt, NQKV, 5120);

  k_attn<<<2048, 256, 0, stream>>>(Q, Kr, Vt, attn);

  k_gemm_bt<1><<<dim3(32, 32), 256, 0, stream>>>(attn, wob, out, 4096, 4096, 4096);
}

// Round 4
// 737.774 us; speedup vs baseline: 1.9783x; 1.0192x over previous
//
#include <hip/hip_runtime.h>
#include <hip/hip_bf16.h>

typedef unsigned short u16;
typedef unsigned int u32;
typedef __bf16 bf16x8 __attribute__((ext_vector_type(8)));
typedef float f32x4 __attribute__((ext_vector_type(4)));
typedef u16 u16x8 __attribute__((ext_vector_type(8)));

#define B_ 2
#define S_ 2048
#define NH 32
#define NKV 8
#define HD 128
#define DIM_ 4096
#define NQKV 6144  // fused projection width: 4096 Q + 1024 K + 1024 V

__device__ inline u16 f2b(float f) {
  u32 u = __builtin_bit_cast(u32, f);
  u = (u + 0x7fffu + ((u >> 16) & 1u)) >> 16;
  return (u16)u;
}
__device__ inline float b2f(u16 b) {
  u32 u = ((u32)b) << 16;
  return __builtin_bit_cast(float, u);
}

__device__ inline void gload_lds16(const u16* g, u16* l) {
  __builtin_amdgcn_global_load_lds((__attribute__((address_space(1))) void*)g,
                                   (__attribute__((address_space(3))) void*)l, 16, 0, 0);
}

// ---------------- f32 -> bf16 cast ----------------
__global__ __launch_bounds__(256) void k_f32_to_bf16(const float* __restrict__ in,
                                                     u16* __restrict__ out, int n4) {
  int i = blockIdx.x * 256 + threadIdx.x;
  if (i >= n4) return;
  const float4 v = ((const float4*)in)[i];
  u32 lo = (u32)f2b(v.x) | ((u32)f2b(v.y) << 16);
  u32 hi = (u32)f2b(v.z) | ((u32)f2b(v.w) << 16);
  ((u32*)out)[(size_t)i * 2] = lo;
  ((u32*)out)[(size_t)i * 2 + 1] = hi;
}

// ---------------- GEMM: C[M][N] = A[M][K] * B[N][K]^T, bf16 in, f32 acc ----------------
// m97 structure + 2D-chunked XCD-aware tile swizzle (each XCD owns a CMxCN tile rect).
// MT x NT tile grid; XCD factorization (MT/CM) x (NT/CN) must equal 8.
template <int N, int K, int OUTF32, int MT, int NT, int CM, int CN>
__global__ __launch_bounds__(256) void k_gemm_bt(const u16* __restrict__ A,
                                                 const u16* __restrict__ Bm,
                                                 void* __restrict__ Cout) {
  constexpr int BK = 64;
  __shared__ __align__(16) u16 As[128 * BK];
  __shared__ __align__(16) u16 Bs[128 * BK];
  // --- XCD chunk decode: xcd = bid&7 (round-robin dispatch), chunk = CM x CN rect ---
  const int bid = blockIdx.x;
  const int xcd = bid & 7, slot = bid >> 3;
  constexpr int XM = MT / CM;  // 2
  const int xm = xcd & (XM - 1);
  const int xn = xcd / XM;
  const int m0 = (xm * CM + (slot % CM)) * 128;
  const int n0 = (xn * CN + (slot / CM)) * 128;
  const int tid = threadIdx.x;
  const int lane = tid & 63, wid = tid >> 6;
  const int wr = wid >> 1, wc = wid & 1;
  const int lr = lane & 15, lg = lane >> 4;
  f32x4 acc[4][4] = {};
  const int srow = tid >> 3, scol = (tid & 7) * 8;
  const u16* ap = A + (size_t)(m0 + srow) * K + scol;
  const u16* bp = Bm + (size_t)(n0 + srow) * K + scol;
  for (int k0 = 0; k0 < K; k0 += BK) {
#pragma unroll
    for (int i = 0; i < 4; ++i) {
      gload_lds16(ap + (size_t)(32 * i) * K + k0, &As[i * 2048 + wid * 512]);
      gload_lds16(bp + (size_t)(32 * i) * K + k0, &Bs[i * 2048 + wid * 512]);
    }
    __syncthreads();
#pragma unroll
    for (int ks = 0; ks < 2; ++ks) {
      bf16x8 af[4], bfr[4];
#pragma unroll
      for (int mi = 0; mi < 4; ++mi)
        af[mi] = *(const bf16x8*)&As[(wr * 64 + mi * 16 + lr) * BK + ks * 32 + lg * 8];
#pragma unroll
      for (int ni = 0; ni < 4; ++ni)
        bfr[ni] = *(const bf16x8*)&Bs[(wc * 64 + ni * 16 + lr) * BK + ks * 32 + lg * 8];
#pragma unroll
      for (int mi = 0; mi < 4; ++mi)
#pragma unroll
        for (int ni = 0; ni < 4; ++ni)
          acc[mi][ni] = __builtin_amdgcn_mfma_f32_16x16x32_bf16(af[mi], bfr[ni], acc[mi][ni], 0, 0, 0);
    }
    __syncthreads();
  }
#pragma unroll
  for (int mi = 0; mi < 4; ++mi) {
    const int r = m0 + wr * 64 + mi * 16 + lg * 4;
#pragma unroll
    for (int ni = 0; ni < 4; ++ni) {
      const int cc = n0 + wc * 64 + ni * 16 + lr;
#pragma unroll
      for (int j = 0; j < 4; ++j) {
        float v = acc[mi][ni][j];
        if (OUTF32)
          ((float*)Cout)[(size_t)(r + j) * N + cc] = v;
        else
          ((u16*)Cout)[(size_t)(r + j) * N + cc] = f2b(v);
      }
    }
  }
}

// ---------------- RoPE + permute [B][S][RS-cols] -> [B][H][S][D] ----------------
__global__ __launch_bounds__(256) void k_rope_perm(const u16* __restrict__ src,
                                                   u16* __restrict__ dst,
                                                   const float* __restrict__ cosb,
                                                   const float* __restrict__ sinb, int H,
                                                   int rs, int coloff) {
  const int row = blockIdx.x * 4 + (threadIdx.x >> 6);
  const int lane = threadIdx.x & 63;
  const int s = row & (S_ - 1);
  const int h = (row >> 11) % H;
  const int b = row / (S_ * H);
  const u16* sp = src + ((size_t)b * S_ + s) * rs + coloff + h * HD + lane * 2;
  const u32 u = *(const u32*)sp;
  const float f0 = b2f((u16)(u & 0xffffu));
  const float f1 = b2f((u16)(u >> 16));
  const float c = cosb[s * 64 + lane];
  const float sn = sinb[s * 64 + lane];
  const float r0 = f0 * c - f1 * sn;
  const float r1 = f0 * sn + f1 * c;
  const u32 o = (u32)f2b(r0) | ((u32)f2b(r1) << 16);
  *(u32*)(dst + (size_t)row * HD + lane * 2) = o;
}

// ---------------- V transpose: [B][S][rs cols @coloff] -> [B][NKV][HD][S] ----------------
__global__ __launch_bounds__(256) void k_transpose_v(const u16* __restrict__ vp,
                                                     u16* __restrict__ vt, int rs, int coloff) {
  __shared__ u16 tile[64][72];
  const int s0 = blockIdx.x * 64, d0 = blockIdx.y * 64;
  const int b = blockIdx.z >> 3, kvh = blockIdx.z & 7;
  const int tid = threadIdx.x;
  const int r = tid >> 3, c8 = (tid & 7) * 8;
#pragma unroll
  for (int i = 0; i < 2; ++i) {
    const int sl = r + 32 * i;
    *(u16x8*)&tile[sl][c8] =
        *(const u16x8*)&vp[((size_t)b * S_ + s0 + sl) * rs + coloff + kvh * HD + d0 + c8];
  }
  __syncthreads();
#pragma unroll
  for (int i = 0; i < 2; ++i) {
    const int dl = r + 32 * i;
    u16x8 o;
#pragma unroll
    for (int j = 0; j < 8; ++j) o[j] = tile[c8 + j][dl];
    *(u16x8*)&vt[(((size_t)b * NKV + kvh) * HD + d0 + dl) * S_ + s0 + c8] = o;
  }
}

// ---------------- Flash attention, causal, GQA rep=4 ----------------
// XCD-aware decode: each XCD owns 2 (b,kvh) groups -> K+V working set 2MB, L2-resident.
// Double-buffered async LDS staging (global_load_lds, linear dest, pre-swizzled source).
__global__ __launch_bounds__(256) void k_attn(const u16* __restrict__ Qg,
                                              const u16* __restrict__ Kg,
                                              const u16* __restrict__ Vtg,
                                              u16* __restrict__ Og) {
  constexpr int QB = 64, KB = 64;
  __shared__ __align__(16) u16 Ks[2][KB * HD];   // 2 x 16KB, rows 256B, XOR-swizzled
  __shared__ __align__(16) u16 Vs[2][HD * KB];   // 2 x 16KB, rows 128B, XOR-swizzled
  __shared__ u16 Ps[4][16][KB + 8];              // per-wave private P
  const int bid = blockIdx.x;
  const int xcd = bid & 7, slot = bid >> 3;
  const int g = xcd * 2 + (slot >> 7);    // (b,kvh) group 0..15
  const int r_ = slot & 127;
  const int hq = r_ & 3;
  const int qt = 31 - (r_ >> 2);          // longest blocks first
  const int b = g >> 3, kvh = g & 7, h = kvh * 4 + hq;
  const int tid = threadIdx.x, wid = tid >> 6, lane = tid & 63;
  const int lr = lane & 15, lg = lane >> 4;
  const int q0 = qt * QB;
  const u16* qp = Qg + (((size_t)b * NH + h) * S_ + q0 + wid * 16 + lr) * HD + lg * 8;
  bf16x8 qf[4];
#pragma unroll
  for (int ks = 0; ks < 4; ++ks) qf[ks] = *(const bf16x8*)(qp + ks * 32);
  f32x4 o[8] = {};
  float mrun[4], lrun[4];
#pragma unroll
  for (int j = 0; j < 4; ++j) { mrun[j] = -1e30f; lrun[j] = 0.f; }
  const u16* kb2 = Kg + ((size_t)b * NKV + kvh) * (size_t)S_ * HD;
  const u16* vb2 = Vtg + ((size_t)b * NKV + kvh) * (size_t)HD * S_;

#define STAGE_KV(BUF, T)                                                              \
  {                                                                                   \
    _Pragma("unroll") for (int i = 0; i < 4; ++i) {                                   \
      const int kr = wid * 16 + i * 4 + (lane >> 4);                                  \
      gload_lds16(kb2 + (size_t)((T) * KB + kr) * HD + ((lane & 15) ^ (kr & 7)) * 8,  \
                  &Ks[BUF][(wid * 16 + i * 4) * HD]);                                 \
    }                                                                                 \
    _Pragma("unroll") for (int i = 0; i < 4; ++i) {                                   \
      const int dr = wid * 32 + i * 8 + (lane >> 3);                                  \
      gload_lds16(vb2 + (size_t)dr * S_ + (T) * KB + ((lane & 7) ^ (dr & 7)) * 8,     \
                  &Vs[BUF][(wid * 32 + i * 8) * KB]);                                 \
    }                                                                                 \
  }

  STAGE_KV(0, 0);
  asm volatile("s_waitcnt vmcnt(0)" ::: "memory");
  __builtin_amdgcn_sched_barrier(0);
  __builtin_amdgcn_s_barrier();
  __builtin_amdgcn_sched_barrier(0);
  int cur = 0;
  for (int t = 0; t <= qt; ++t) {
    if (t < qt) STAGE_KV(cur ^ 1, t + 1);
    __builtin_amdgcn_sched_barrier(0);
    const char* KsB = (const char*)&Ks[cur][0];
    const char* VsB = (const char*)&Vs[cur][0];
    f32x4 s[4] = {};
#pragma unroll
    for (int ks = 0; ks < 4; ++ks) {
      bf16x8 kf4[4];
#pragma unroll
      for (int n = 0; n < 4; ++n) {
        const int rr = n * 16 + lr;
        kf4[n] = *(const bf16x8*)(KsB + rr * 256 + ((ks * 64 + lg * 16) ^ ((rr & 7) << 4)));
      }
#pragma unroll
      for (int n = 0; n < 4; ++n)
        s[n] = __builtin_amdgcn_mfma_f32_16x16x32_bf16(qf[ks], kf4[n], s[n], 0, 0, 0);
    }
    const float scale = 0.08838834764831845f;
    float sv[4][4], pm[4];
#pragma unroll
    for (int j = 0; j < 4; ++j) pm[j] = -1e30f;
    const bool diag = (t == qt);
#pragma unroll
    for (int n = 0; n < 4; ++n)
#pragma unroll
      for (int j = 0; j < 4; ++j) {
        float v = s[n][j] * scale;
        if (diag && (n * 16 + lr > wid * 16 + lg * 4 + j)) v = -1e30f;  // causal
        sv[n][j] = v;
        pm[j] = fmaxf(pm[j], v);
      }
#pragma unroll
    for (int off = 1; off < 16; off <<= 1)
#pragma unroll
      for (int j = 0; j < 4; ++j) pm[j] = fmaxf(pm[j], __shfl_xor(pm[j], off));
    float al[4];
#pragma unroll
    for (int j = 0; j < 4; ++j) {
      const float mt = fmaxf(mrun[j], pm[j]);
      al[j] = __expf(mrun[j] - mt);
      mrun[j] = mt;
    }
    float ls[4] = {0.f, 0.f, 0.f, 0.f};
#pragma unroll
    for (int n = 0; n < 4; ++n)
#pragma unroll
      for (int j = 0; j < 4; ++j) {
        const float p = __expf(sv[n][j] - mrun[j]);
        ls[j] += p;
        Ps[wid][lg * 4 + j][n * 16 + lr] = f2b(p);
      }
#pragma unroll
    for (int off = 1; off < 16; off <<= 1)
#pragma unroll
      for (int j = 0; j < 4; ++j) ls[j] += __shfl_xor(ls[j], off);
#pragma unroll
    for (int j = 0; j < 4; ++j) lrun[j] = lrun[j] * al[j] + ls[j];
#pragma unroll
    for (int c = 0; c < 8; ++c)
#pragma unroll
      for (int j = 0; j < 4; ++j) o[c][j] *= al[j];
    asm volatile("s_waitcnt lgkmcnt(0)" ::: "memory");
    __builtin_amdgcn_sched_barrier(0);
#pragma unroll
    for (int ks = 0; ks < 2; ++ks) {
      bf16x8 af = *(const bf16x8*)&Ps[wid][lr][ks * 32 + lg * 8];
#pragma unroll
      for (int c = 0; c < 8; ++c) {
        const int rv = c * 16 + lr;
        bf16x8 vf = *(const bf16x8*)(VsB + rv * 128 + ((ks * 64 + lg * 16) ^ ((rv & 7) << 4)));
        o[c] = __builtin_amdgcn_mfma_f32_16x16x32_bf16(af, vf, o[c], 0, 0, 0);
      }
    }
    asm volatile("s_waitcnt vmcnt(0)" ::: "memory");
    __builtin_amdgcn_sched_barrier(0);
    __builtin_amdgcn_s_barrier();
    __builtin_amdgcn_sched_barrier(0);
    cur ^= 1;
  }
#undef STAGE_KV
#pragma unroll
  for (int c = 0; c < 8; ++c)
#pragma unroll
    for (int j = 0; j < 4; ++j) {
      const int srow = q0 + wid * 16 + lg * 4 + j;
      const float v = o[c][j] / lrun[j];
      Og[((size_t)b * S_ + srow) * (NH * HD) + h * HD + c * 16 + lr] = f2b(v);
    }
}

extern "C" void kernel_launch(void* const* d_in, const int* in_sizes, int n_in,
                              void* d_out, int out_size, void* d_ws, size_t ws_size,
                              hipStream_t stream) {
  const float* x = (const float*)d_in[0];
  const float* fc = (const float*)d_in[1];
  const float* fs = (const float*)d_in[2];
  // d_in[3] positions (identity), d_in[4] mask (pure causal: WINDOW>=SEQ) -- analytic
  const float* wq = (const float*)d_in[5];
  const float* wk = (const float*)d_in[6];
  const float* wv = (const float*)d_in[7];
  const float* wo = (const float*)d_in[8];
  char* ws = (char*)d_ws;
  const size_t MB = 1024 * 1024;
  u16* xb = (u16*)(ws);                  // 32 MB  [4096][4096]
  u16* wqkvb = (u16*)(ws + 32 * MB);     // 48 MB  [6144][4096]
  u16* wkb = wqkvb + (size_t)4096 * 4096;
  u16* wvb = wqkvb + (size_t)5120 * 4096;
  u16* wob = (u16*)(ws + 80 * MB);       // 32 MB
  u16* qkvp = (u16*)(ws + 112 * MB);     // 48 MB  [B*S=4096][6144]
  // liveness reuse:
  u16* Q = xb;                           // [B][NH][S][HD] (xb free after qkv gemm)
  u16* Kr = (u16*)(ws + 32 * MB);        // 8 MB
  u16* Vt = (u16*)(ws + 40 * MB);        // 8 MB
  u16* attn = (u16*)(ws + 48 * MB);      // 32 MB
  float* out = (float*)d_out;

  k_f32_to_bf16<<<16384, 256, 0, stream>>>(x, xb, 4194304);
  k_f32_to_bf16<<<16384, 256, 0, stream>>>(wq, wqkvb, 4194304);
  k_f32_to_bf16<<<4096, 256, 0, stream>>>(wk, wkb, 1048576);
  k_f32_to_bf16<<<4096, 256, 0, stream>>>(wv, wvb, 1048576);
  k_f32_to_bf16<<<16384, 256, 0, stream>>>(wo, wob, 4194304);

  // fused QKV projection: [4096][4096] x [6144][4096]^T -> [4096][6144]
  // 32x48 tiles, XCD chunks 16x12 (2x4 factorization)
  k_gemm_bt<NQKV, 4096, 0, 32, 48, 16, 12><<<1536, 256, 0, stream>>>(xb, wqkvb, qkvp);

  k_rope_perm<<<32768, 256, 0, stream>>>(qkvp, Q, fc, fs, NH, NQKV, 0);
  k_rope_perm<<<8192, 256, 0, stream>>>(qkvp, Kr, fc, fs, NKV, NQKV, 4096);
  k_transpose_v<<<dim3(32, 2, 16), 256, 0, stream>>>(qkvp, Vt, NQKV, 5120);

  k_attn<<<2048, 256, 0, stream>>>(Q, Kr, Vt, attn);

  // O projection: 32x32 tiles, XCD chunks 16x8
  k_gemm_bt<4096, 4096, 1, 32, 32, 16, 8><<<1024, 256, 0, stream>>>(attn, wob, out);
}

// Round 5
// 573.657 us; speedup vs baseline: 2.5443x; 1.2861x over previous
//
#include <hip/hip_runtime.h>
#include <hip/hip_bf16.h>

typedef unsigned short u16;
typedef unsigned int u32;
typedef __bf16 bf16x8 __attribute__((ext_vector_type(8)));
typedef float f32x4 __attribute__((ext_vector_type(4)));
typedef u16 u16x8 __attribute__((ext_vector_type(8)));

#define B_ 2
#define S_ 2048
#define NH 32
#define NKV 8
#define HD 128
#define DIM_ 4096
#define NQKV 6144  // fused projection width: 4096 Q + 1024 K + 1024 V

__device__ inline u16 f2b(float f) {
  u32 u = __builtin_bit_cast(u32, f);
  u = (u + 0x7fffu + ((u >> 16) & 1u)) >> 16;
  return (u16)u;
}
__device__ inline float b2f(u16 b) {
  u32 u = ((u32)b) << 16;
  return __builtin_bit_cast(float, u);
}

__device__ inline void gload_lds16(const u16* g, u16* l) {
  __builtin_amdgcn_global_load_lds((__attribute__((address_space(1))) void*)g,
                                   (__attribute__((address_space(3))) void*)l, 16, 0, 0);
}

// ---------------- f32 -> bf16 cast ----------------
__global__ __launch_bounds__(256) void k_f32_to_bf16(const float* __restrict__ in,
                                                     u16* __restrict__ out, int n4) {
  int i = blockIdx.x * 256 + threadIdx.x;
  if (i >= n4) return;
  const float4 v = ((const float4*)in)[i];
  u32 lo = (u32)f2b(v.x) | ((u32)f2b(v.y) << 16);
  u32 hi = (u32)f2b(v.z) | ((u32)f2b(v.w) << 16);
  ((u32*)out)[(size_t)i * 2] = lo;
  ((u32*)out)[(size_t)i * 2 + 1] = hi;
}

// ================= 256x256 8-phase GEMM: C = A[M][K] * B[N][K]^T =================
// 8 waves (2m x 4n), per-wave out 128x64, BK=64, LDS 128KB double-buffered.
// Tile t -> buf[t&1]. During tile t's 4 phases, tile t+1 is staged into buf[t+1&1]
// (dead since tile t-1 finished). Counted vmcnt: phase-1-end vmcnt(4) publishes the
// prev tile's floating A-i1 loads (rows 64-127) before phase 2 reads them; boundary
// vmcnt(2) lets the new tile's A-i1 float across (lands rows 64-127 while phases 0-1
// read rows 0-63). LDS XOR swizzle: LDS(row, cc) holds global k-chunk cc^(row&7).
template <int N, int K, int OUTF32, int MT, int NT, int CM, int CN>
__global__ __launch_bounds__(512, 2) void k_gemm256(const u16* __restrict__ A,
                                                    const u16* __restrict__ Bm,
                                                    void* __restrict__ Cout) {
  __shared__ __align__(16) u16 lds[2][4][128 * 64];  // [buf][Ah0,Ah1,Bh0,Bh1]
  const int bid = blockIdx.x;
  const int xcd = bid & 7, slot = bid >> 3;
  constexpr int XM = MT / CM;
  const int xm = xcd % XM, xn = xcd / XM;
  const int m0 = (xm * CM + slot % CM) * 256;
  const int n0 = (xn * CN + slot / CM) * 256;
  const int tid = threadIdx.x, w = tid >> 6, lane = tid & 63;
  const int wm = w >> 2, wn = w & 3;
  const int lr = lane & 15, lg = lane >> 4;
  const int lrow8 = lane >> 3;                      // row within 8-row group
  const int gcol = ((lane & 7) ^ lrow8) * 8;        // pre-swizzled source k-col (u16)
  f32x4 acc[8][4] = {};
  const u16* gsrc[4];
  gsrc[0] = A + (size_t)(m0) * K;
  gsrc[1] = A + (size_t)(m0 + 128) * K;
  gsrc[2] = Bm + (size_t)(n0) * K;
  gsrc[3] = Bm + (size_t)(n0 + 128) * K;

  // one wave-instr: 8 rows x 128B (i=0: rows 0-63 across waves, i=1: rows 64-127)
#define SG(DST, PART, I, KN)                                                          \
  gload_lds16(gsrc[PART] + (size_t)((I) * 64 + w * 8 + lrow8) * K + (KN) + gcol,      \
              &lds[DST][PART][((I) * 8 + w) * 512])

#define BARRIER_()                      \
  __builtin_amdgcn_sched_barrier(0);    \
  __builtin_amdgcn_s_barrier();         \
  __builtin_amdgcn_sched_barrier(0)

  // TILE: compute K-tile in buf BB; if HS, stage next tile (k-col KN) into buf BB^1.
  // LASTVM: 2 = steady boundary vmcnt(2); 9 = drain vmcnt(0); 0 = none (final tile).
#define TILE(BB, HS, KN, LASTVM)                                                      \
  {                                                                                   \
    const u16* Abase = &lds[BB][wm][0];                                               \
    const u16* Bbase = &lds[BB][2 + (wn >> 1)][(wn & 1) * 64 * 64];                   \
    bf16x8 bfr[4][2];                                                                 \
    _Pragma("unroll") for (int p = 0; p < 4; ++p) {                                   \
      if (HS) {                                                                       \
        if (p == 0) { SG(BB ^ 1, 0, 0, KN); SG(BB ^ 1, 1, 0, KN); }                   \
        if (p == 1) { SG(BB ^ 1, 2, 0, KN); SG(BB ^ 1, 2, 1, KN); }                   \
        if (p == 2) { SG(BB ^ 1, 3, 0, KN); SG(BB ^ 1, 3, 1, KN); }                   \
        if (p == 3) { SG(BB ^ 1, 0, 1, KN); SG(BB ^ 1, 1, 1, KN); }                   \
      }                                                                               \
      bf16x8 af[2][2];                                                                \
      _Pragma("unroll") for (int mi = 0; mi < 2; ++mi)                                \
        _Pragma("unroll") for (int ks = 0; ks < 2; ++ks)                              \
          af[mi][ks] = *(const bf16x8*)&Abase[((p * 2 + mi) * 16 + lr) * 64 +         \
                                              (((ks * 4 + lg) ^ (lr & 7)) * 8)];      \
      if (p == 0) {                                                                   \
        _Pragma("unroll") for (int nf = 0; nf < 4; ++nf)                              \
          _Pragma("unroll") for (int ks = 0; ks < 2; ++ks)                            \
            bfr[nf][ks] = *(const bf16x8*)&Bbase[(nf * 16 + lr) * 64 +                \
                                                 (((ks * 4 + lg) ^ (lr & 7)) * 8)];   \
      }                                                                               \
      BARRIER_();                                                                     \
      __builtin_amdgcn_s_setprio(1);                                                  \
      _Pragma("unroll") for (int mi = 0; mi < 2; ++mi)                                \
        _Pragma("unroll") for (int nf = 0; nf < 4; ++nf)                              \
          _Pragma("unroll") for (int ks = 0; ks < 2; ++ks)                            \
            acc[p * 2 + mi][nf] = __builtin_amdgcn_mfma_f32_16x16x32_bf16(            \
                af[mi][ks], bfr[nf][ks], acc[p * 2 + mi][nf], 0, 0, 0);               \
      __builtin_amdgcn_s_setprio(0);                                                  \
      if (p == 1 && HS) asm volatile("s_waitcnt vmcnt(4)" ::: "memory");              \
      if (p == 3 && LASTVM == 2) asm volatile("s_waitcnt vmcnt(2)" ::: "memory");     \
      if (p == 3 && LASTVM == 9) asm volatile("s_waitcnt vmcnt(0)" ::: "memory");     \
      BARRIER_();                                                                     \
    }                                                                                 \
  }

  // prologue: stage tile 0 -> buf0, full drain
#pragma unroll
  for (int part = 0; part < 4; ++part) { SG(0, part, 0, 0); SG(0, part, 1, 0); }
  asm volatile("s_waitcnt vmcnt(0)" ::: "memory");
  BARRIER_();

  for (int tt = 0; tt < (K / 64) - 2; tt += 2) {
    TILE(0, 1, (tt + 1) * 64, 2);
    TILE(1, 1, (tt + 2) * 64, 2);
  }
  TILE(0, 1, (K / 64 - 1) * 64, 9);  // tile K/64-2: stage last tile, drain boundary
  TILE(1, 0, 0, 0);                  // final tile: pure compute
#undef TILE
#undef SG

#pragma unroll
  for (int mf = 0; mf < 8; ++mf) {
    const int r = m0 + wm * 128 + mf * 16 + lg * 4;
#pragma unroll
    for (int nf = 0; nf < 4; ++nf) {
      const int cc = n0 + wn * 64 + nf * 16 + lr;
#pragma unroll
      for (int j = 0; j < 4; ++j) {
        float v = acc[mf][nf][j];
        if (OUTF32)
          ((float*)Cout)[(size_t)(r + j) * N + cc] = v;
        else
          ((u16*)Cout)[(size_t)(r + j) * N + cc] = f2b(v);
      }
    }
  }
}

// ---------------- RoPE + permute [B][S][RS-cols] -> [B][H][S][D] ----------------
__global__ __launch_bounds__(256) void k_rope_perm(const u16* __restrict__ src,
                                                   u16* __restrict__ dst,
                                                   const float* __restrict__ cosb,
                                                   const float* __restrict__ sinb, int H,
                                                   int rs, int coloff) {
  const int row = blockIdx.x * 4 + (threadIdx.x >> 6);
  const int lane = threadIdx.x & 63;
  const int s = row & (S_ - 1);
  const int h = (row >> 11) % H;
  const int b = row / (S_ * H);
  const u16* sp = src + ((size_t)b * S_ + s) * rs + coloff + h * HD + lane * 2;
  const u32 u = *(const u32*)sp;
  const float f0 = b2f((u16)(u & 0xffffu));
  const float f1 = b2f((u16)(u >> 16));
  const float c = cosb[s * 64 + lane];
  const float sn = sinb[s * 64 + lane];
  const float r0 = f0 * c - f1 * sn;
  const float r1 = f0 * sn + f1 * c;
  const u32 o = (u32)f2b(r0) | ((u32)f2b(r1) << 16);
  *(u32*)(dst + (size_t)row * HD + lane * 2) = o;
}

// ---------------- V transpose: [B][S][rs cols @coloff] -> [B][NKV][HD][S] ----------------
__global__ __launch_bounds__(256) void k_transpose_v(const u16* __restrict__ vp,
                                                     u16* __restrict__ vt, int rs, int coloff) {
  __shared__ u16 tile[64][72];
  const int s0 = blockIdx.x * 64, d0 = blockIdx.y * 64;
  const int b = blockIdx.z >> 3, kvh = blockIdx.z & 7;
  const int tid = threadIdx.x;
  const int r = tid >> 3, c8 = (tid & 7) * 8;
#pragma unroll
  for (int i = 0; i < 2; ++i) {
    const int sl = r + 32 * i;
    *(u16x8*)&tile[sl][c8] =
        *(const u16x8*)&vp[((size_t)b * S_ + s0 + sl) * rs + coloff + kvh * HD + d0 + c8];
  }
  __syncthreads();
#pragma unroll
  for (int i = 0; i < 2; ++i) {
    const int dl = r + 32 * i;
    u16x8 o;
#pragma unroll
    for (int j = 0; j < 8; ++j) o[j] = tile[c8 + j][dl];
    *(u16x8*)&vt[(((size_t)b * NKV + kvh) * HD + d0 + dl) * S_ + s0 + c8] = o;
  }
}

// ---------------- Flash attention, causal, GQA rep=4 ----------------
__global__ __launch_bounds__(256) void k_attn(const u16* __restrict__ Qg,
                                              const u16* __restrict__ Kg,
                                              const u16* __restrict__ Vtg,
                                              u16* __restrict__ Og) {
  constexpr int QB = 64, KB = 64;
  __shared__ __align__(16) u16 Ks[2][KB * HD];   // 2 x 16KB, rows 256B, XOR-swizzled
  __shared__ __align__(16) u16 Vs[2][HD * KB];   // 2 x 16KB, rows 128B, XOR-swizzled
  __shared__ u16 Ps[4][16][KB + 8];              // per-wave private P
  const int bid = blockIdx.x;
  const int xcd = bid & 7, slot = bid >> 3;
  const int g = xcd * 2 + (slot >> 7);    // (b,kvh) group 0..15
  const int r_ = slot & 127;
  const int hq = r_ & 3;
  const int qt = 31 - (r_ >> 2);          // longest blocks first
  const int b = g >> 3, kvh = g & 7, h = kvh * 4 + hq;
  const int tid = threadIdx.x, wid = tid >> 6, lane = tid & 63;
  const int lr = lane & 15, lg = lane >> 4;
  const int q0 = qt * QB;
  const u16* qp = Qg + (((size_t)b * NH + h) * S_ + q0 + wid * 16 + lr) * HD + lg * 8;
  bf16x8 qf[4];
#pragma unroll
  for (int ks = 0; ks < 4; ++ks) qf[ks] = *(const bf16x8*)(qp + ks * 32);
  f32x4 o[8] = {};
  float mrun[4], lrun[4];
#pragma unroll
  for (int j = 0; j < 4; ++j) { mrun[j] = -1e30f; lrun[j] = 0.f; }
  const u16* kb2 = Kg + ((size_t)b * NKV + kvh) * (size_t)S_ * HD;
  const u16* vb2 = Vtg + ((size_t)b * NKV + kvh) * (size_t)HD * S_;

#define STAGE_KV(BUF, T)                                                              \
  {                                                                                   \
    _Pragma("unroll") for (int i = 0; i < 4; ++i) {                                   \
      const int kr = wid * 16 + i * 4 + (lane >> 4);                                  \
      gload_lds16(kb2 + (size_t)((T) * KB + kr) * HD + ((lane & 15) ^ (kr & 7)) * 8,  \
                  &Ks[BUF][(wid * 16 + i * 4) * HD]);                                 \
    }                                                                                 \
    _Pragma("unroll") for (int i = 0; i < 4; ++i) {                                   \
      const int dr = wid * 32 + i * 8 + (lane >> 3);                                  \
      gload_lds16(vb2 + (size_t)dr * S_ + (T) * KB + ((lane & 7) ^ (dr & 7)) * 8,     \
                  &Vs[BUF][(wid * 32 + i * 8) * KB]);                                 \
    }                                                                                 \
  }

  STAGE_KV(0, 0);
  asm volatile("s_waitcnt vmcnt(0)" ::: "memory");
  __builtin_amdgcn_sched_barrier(0);
  __builtin_amdgcn_s_barrier();
  __builtin_amdgcn_sched_barrier(0);
  int cur = 0;
  for (int t = 0; t <= qt; ++t) {
    if (t < qt) STAGE_KV(cur ^ 1, t + 1);
    __builtin_amdgcn_sched_barrier(0);
    const char* KsB = (const char*)&Ks[cur][0];
    const char* VsB = (const char*)&Vs[cur][0];
    f32x4 s[4] = {};
#pragma unroll
    for (int ks = 0; ks < 4; ++ks) {
      bf16x8 kf4[4];
#pragma unroll
      for (int n = 0; n < 4; ++n) {
        const int rr = n * 16 + lr;
        kf4[n] = *(const bf16x8*)(KsB + rr * 256 + ((ks * 64 + lg * 16) ^ ((rr & 7) << 4)));
      }
#pragma unroll
      for (int n = 0; n < 4; ++n)
        s[n] = __builtin_amdgcn_mfma_f32_16x16x32_bf16(qf[ks], kf4[n], s[n], 0, 0, 0);
    }
    const float scale = 0.08838834764831845f;
    float sv[4][4], pm[4];
#pragma unroll
    for (int j = 0; j < 4; ++j) pm[j] = -1e30f;
    const bool diag = (t == qt);
#pragma unroll
    for (int n = 0; n < 4; ++n)
#pragma unroll
      for (int j = 0; j < 4; ++j) {
        float v = s[n][j] * scale;
        if (diag && (n * 16 + lr > wid * 16 + lg * 4 + j)) v = -1e30f;  // causal
        sv[n][j] = v;
        pm[j] = fmaxf(pm[j], v);
      }
#pragma unroll
    for (int off = 1; off < 16; off <<= 1)
#pragma unroll
      for (int j = 0; j < 4; ++j) pm[j] = fmaxf(pm[j], __shfl_xor(pm[j], off));
    float al[4];
#pragma unroll
    for (int j = 0; j < 4; ++j) {
      const float mt = fmaxf(mrun[j], pm[j]);
      al[j] = __expf(mrun[j] - mt);
      mrun[j] = mt;
    }
    float ls[4] = {0.f, 0.f, 0.f, 0.f};
#pragma unroll
    for (int n = 0; n < 4; ++n)
#pragma unroll
      for (int j = 0; j < 4; ++j) {
        const float p = __expf(sv[n][j] - mrun[j]);
        ls[j] += p;
        Ps[wid][lg * 4 + j][n * 16 + lr] = f2b(p);
      }
#pragma unroll
    for (int off = 1; off < 16; off <<= 1)
#pragma unroll
      for (int j = 0; j < 4; ++j) ls[j] += __shfl_xor(ls[j], off);
#pragma unroll
    for (int j = 0; j < 4; ++j) lrun[j] = lrun[j] * al[j] + ls[j];
#pragma unroll
    for (int c = 0; c < 8; ++c)
#pragma unroll
      for (int j = 0; j < 4; ++j) o[c][j] *= al[j];
    asm volatile("s_waitcnt lgkmcnt(0)" ::: "memory");
    __builtin_amdgcn_sched_barrier(0);
#pragma unroll
    for (int ks = 0; ks < 2; ++ks) {
      bf16x8 af = *(const bf16x8*)&Ps[wid][lr][ks * 32 + lg * 8];
#pragma unroll
      for (int c = 0; c < 8; ++c) {
        const int rv = c * 16 + lr;
        bf16x8 vf = *(const bf16x8*)(VsB + rv * 128 + ((ks * 64 + lg * 16) ^ ((rv & 7) << 4)));
        o[c] = __builtin_amdgcn_mfma_f32_16x16x32_bf16(af, vf, o[c], 0, 0, 0);
      }
    }
    asm volatile("s_waitcnt vmcnt(0)" ::: "memory");
    __builtin_amdgcn_sched_barrier(0);
    __builtin_amdgcn_s_barrier();
    __builtin_amdgcn_sched_barrier(0);
    cur ^= 1;
  }
#undef STAGE_KV
#pragma unroll
  for (int c = 0; c < 8; ++c)
#pragma unroll
    for (int j = 0; j < 4; ++j) {
      const int srow = q0 + wid * 16 + lg * 4 + j;
      const float v = o[c][j] / lrun[j];
      Og[((size_t)b * S_ + srow) * (NH * HD) + h * HD + c * 16 + lr] = f2b(v);
    }
}

extern "C" void kernel_launch(void* const* d_in, const int* in_sizes, int n_in,
                              void* d_out, int out_size, void* d_ws, size_t ws_size,
                              hipStream_t stream) {
  const float* x = (const float*)d_in[0];
  const float* fc = (const float*)d_in[1];
  const float* fs = (const float*)d_in[2];
  // d_in[3] positions (identity), d_in[4] mask (pure causal: WINDOW>=SEQ) -- analytic
  const float* wq = (const float*)d_in[5];
  const float* wk = (const float*)d_in[6];
  const float* wv = (const float*)d_in[7];
  const float* wo = (const float*)d_in[8];
  char* ws = (char*)d_ws;
  const size_t MB = 1024 * 1024;
  u16* xb = (u16*)(ws);                  // 32 MB  [4096][4096]
  u16* wqkvb = (u16*)(ws + 32 * MB);     // 48 MB  [6144][4096]
  u16* wkb = wqkvb + (size_t)4096 * 4096;
  u16* wvb = wqkvb + (size_t)5120 * 4096;
  u16* wob = (u16*)(ws + 80 * MB);       // 32 MB
  u16* qkvp = (u16*)(ws + 112 * MB);     // 48 MB  [B*S=4096][6144]
  // liveness reuse:
  u16* Q = xb;                           // [B][NH][S][HD] (xb free after qkv gemm)
  u16* Kr = (u16*)(ws + 32 * MB);        // 8 MB
  u16* Vt = (u16*)(ws + 40 * MB);        // 8 MB
  u16* attn = (u16*)(ws + 48 * MB);      // 32 MB
  float* out = (float*)d_out;

  k_f32_to_bf16<<<16384, 256, 0, stream>>>(x, xb, 4194304);
  k_f32_to_bf16<<<16384, 256, 0, stream>>>(wq, wqkvb, 4194304);
  k_f32_to_bf16<<<4096, 256, 0, stream>>>(wk, wkb, 1048576);
  k_f32_to_bf16<<<4096, 256, 0, stream>>>(wv, wvb, 1048576);
  k_f32_to_bf16<<<16384, 256, 0, stream>>>(wo, wob, 4194304);

  // fused QKV projection: 16x24 tiles of 256^2, XCD chunks 8x6 (2x4 factorization)
  k_gemm256<NQKV, 4096, 0, 16, 24, 8, 6><<<384, 512, 0, stream>>>(xb, wqkvb, qkvp);

  k_rope_perm<<<32768, 256, 0, stream>>>(qkvp, Q, fc, fs, NH, NQKV, 0);
  k_rope_perm<<<8192, 256, 0, stream>>>(qkvp, Kr, fc, fs, NKV, NQKV, 4096);
  k_transpose_v<<<dim3(32, 2, 16), 256, 0, stream>>>(qkvp, Vt, NQKV, 5120);

  k_attn<<<2048, 256, 0, stream>>>(Q, Kr, Vt, attn);

  // O projection: 16x16 tiles of 256^2, XCD chunks 8x4
  k_gemm256<4096, 4096, 1, 16, 16, 8, 4><<<256, 512, 0, stream>>>(attn, wob, out);
}

// Round 6
// 533.433 us; speedup vs baseline: 2.7362x; 1.0754x over previous
//
#include <hip/hip_runtime.h>
#include <hip/hip_bf16.h>

typedef unsigned short u16;
typedef unsigned int u32;
typedef __bf16 bf16x8 __attribute__((ext_vector_type(8)));
typedef float f32x4 __attribute__((ext_vector_type(4)));
typedef u16 u16x8 __attribute__((ext_vector_type(8)));

#define B_ 2
#define S_ 2048
#define NH 32
#define NKV 8
#define HD 128
#define DIM_ 4096
#define NQKV 6144  // fused projection width: 4096 Q + 1024 K + 1024 V

__device__ inline u16 f2b(float f) {
  u32 u = __builtin_bit_cast(u32, f);
  u = (u + 0x7fffu + ((u >> 16) & 1u)) >> 16;
  return (u16)u;
}
__device__ inline float b2f(u16 b) {
  u32 u = ((u32)b) << 16;
  return __builtin_bit_cast(float, u);
}

__device__ inline void gload_lds16(const u16* g, u16* l) {
  __builtin_amdgcn_global_load_lds((__attribute__((address_space(1))) void*)g,
                                   (__attribute__((address_space(3))) void*)l, 16, 0, 0);
}

// ---------------- f32 -> bf16 cast ----------------
__global__ __launch_bounds__(256) void k_f32_to_bf16(const float* __restrict__ in,
                                                     u16* __restrict__ out, int n4) {
  int i = blockIdx.x * 256 + threadIdx.x;
  if (i >= n4) return;
  const float4 v = ((const float4*)in)[i];
  u32 lo = (u32)f2b(v.x) | ((u32)f2b(v.y) << 16);
  u32 hi = (u32)f2b(v.z) | ((u32)f2b(v.w) << 16);
  ((u32*)out)[(size_t)i * 2] = lo;
  ((u32*)out)[(size_t)i * 2 + 1] = hi;
}

// ================= 256xBN 8-phase GEMM: C = A[M][K] * B[N][K]^T =================
// 8 waves (2m x 4n), per-wave out 128x(BN/4), BK=64, LDS double-buffered.
// 64-row "groups": A = groups 0..3, B = groups 4..4+GB-1 (GB = BN/64).
// LDS(row, chunk16B) holds global k-chunk (chunk ^ (row&7))  [both-sides swizzle].
// Issue order for next tile (2/phase): [B4,B5,(B6),(B7|A0),A0/2..,A1,A3] such that
// the 5 (GB=3) / 6 (GB=4) loads needed at next-p0 come first -> boundary vmcnt(2)
// leaves {A1,A3} in flight; they are needed at p2 -> vmcnt(4) at p1-end.
template <int BN, int N, int K, int OUTF32, int MT, int NT, int CM, int CN>
__global__ __launch_bounds__(512, 2) void k_gemm256(const u16* __restrict__ A,
                                                    const u16* __restrict__ Bm,
                                                    void* __restrict__ Cout) {
  constexpr int GB = BN / 64;
  __shared__ __align__(16) u16 lds[2][4 + GB][64 * 64];
  const int bid = blockIdx.x;
  const int xcd = bid & 7, slot = bid >> 3;
  constexpr int XM = MT / CM;
  const int xm = xcd % XM, xn = xcd / XM;
  const int m0 = (xm * CM + slot % CM) * 256;
  const int n0 = (xn * CN + slot / CM) * BN;
  const int tid = threadIdx.x, w = tid >> 6, lane = tid & 63;
  const int wm = w >> 2, wn = w & 3;
  const int lr = lane & 15, lg = lane >> 4;
  const int lrow8 = lane >> 3;
  const int gcol = ((lane & 7) ^ lrow8) * 8;  // pre-swizzled source k-col (u16)
  f32x4 acc[8][GB] = {};
  const u16* gsrc[4 + GB];
#pragma unroll
  for (int g = 0; g < 4; ++g) gsrc[g] = A + (size_t)(m0 + g * 64) * K;
#pragma unroll
  for (int g = 0; g < GB; ++g) gsrc[4 + g] = Bm + (size_t)(n0 + g * 64) * K;

#define SG(DST, G, KN) \
  gload_lds16(gsrc[G] + (size_t)(w * 8 + lrow8) * K + (KN) + gcol, &lds[DST][G][w * 512])

#define BARRIER_()                      \
  __builtin_amdgcn_sched_barrier(0);    \
  __builtin_amdgcn_s_barrier();         \
  __builtin_amdgcn_sched_barrier(0)

#define TILE(BB, HS, KN, LASTVM)                                                          \
  {                                                                                       \
    const u16* Lb = &lds[BB][0][0];                                                       \
    bf16x8 bfr[GB][2];                                                                    \
    _Pragma("unroll") for (int p = 0; p < 4; ++p) {                                       \
      if (HS) {                                                                           \
        if (p == 0) { SG(BB ^ 1, 4, KN); SG(BB ^ 1, 5, KN); }                             \
        if (p == 1) {                                                                     \
          SG(BB ^ 1, 6, KN);                                                              \
          if constexpr (GB == 4) SG(BB ^ 1, 7, KN); else SG(BB ^ 1, 0, KN);               \
        }                                                                                 \
        if (p == 2) {                                                                     \
          if constexpr (GB == 4) { SG(BB ^ 1, 0, KN); SG(BB ^ 1, 2, KN); }                \
          else { SG(BB ^ 1, 2, KN); SG(BB ^ 1, 1, KN); }                                  \
        }                                                                                 \
        if (p == 3) {                                                                     \
          if constexpr (GB == 4) { SG(BB ^ 1, 1, KN); SG(BB ^ 1, 3, KN); }                \
          else SG(BB ^ 1, 3, KN);                                                         \
        }                                                                                 \
      }                                                                                   \
      bf16x8 af[2][2];                                                                    \
      _Pragma("unroll") for (int mi = 0; mi < 2; ++mi)                                    \
        _Pragma("unroll") for (int ks = 0; ks < 2; ++ks)                                  \
          af[mi][ks] = *(const bf16x8*)&Lb[(size_t)(wm * 2 + ((p * 2 + mi) >> 2)) * 4096 +\
              (((p * 2 + mi) & 3) * 16 + lr) * 64 + ((ks * 4 + lg) ^ (lr & 7)) * 8];      \
      if (p == 0) {                                                                       \
        _Pragma("unroll") for (int nf = 0; nf < GB; ++nf) {                               \
          const int rowB = wn * (BN / 4) + nf * 16 + lr;                                  \
          _Pragma("unroll") for (int ks = 0; ks < 2; ++ks)                                \
            bfr[nf][ks] = *(const bf16x8*)&Lb[(size_t)(4 + (rowB >> 6)) * 4096 +          \
                (rowB & 63) * 64 + ((ks * 4 + lg) ^ (lr & 7)) * 8];                       \
        }                                                                                 \
      }                                                                                   \
      BARRIER_();                                                                         \
      __builtin_amdgcn_s_setprio(1);                                                      \
      _Pragma("unroll") for (int mi = 0; mi < 2; ++mi)                                    \
        _Pragma("unroll") for (int nf = 0; nf < GB; ++nf)                                 \
          _Pragma("unroll") for (int ks = 0; ks < 2; ++ks)                                \
            acc[p * 2 + mi][nf] = __builtin_amdgcn_mfma_f32_16x16x32_bf16(                \
                af[mi][ks], bfr[nf][ks], acc[p * 2 + mi][nf], 0, 0, 0);                   \
      __builtin_amdgcn_s_setprio(0);                                                      \
      if (p == 1 && HS) asm volatile("s_waitcnt vmcnt(4)" ::: "memory");                  \
      if (p == 3 && LASTVM == 2) asm volatile("s_waitcnt vmcnt(2)" ::: "memory");         \
      if (p == 3 && LASTVM == 9) asm volatile("s_waitcnt vmcnt(0)" ::: "memory");         \
      BARRIER_();                                                                         \
    }                                                                                     \
  }

  // prologue: stage tile 0 -> buf0, full drain
#pragma unroll
  for (int g = 0; g < 4 + GB; ++g) SG(0, g, 0);
  asm volatile("s_waitcnt vmcnt(0)" ::: "memory");
  BARRIER_();

  for (int tt = 0; tt < (K / 64) - 2; tt += 2) {
    TILE(0, 1, (tt + 1) * 64, 2);
    TILE(1, 1, (tt + 2) * 64, 2);
  }
  TILE(0, 1, (K / 64 - 1) * 64, 9);
  TILE(1, 0, 0, 0);
#undef TILE
#undef SG

#pragma unroll
  for (int mf = 0; mf < 8; ++mf) {
    const int r = m0 + wm * 128 + mf * 16 + lg * 4;
#pragma unroll
    for (int nf = 0; nf < GB; ++nf) {
      const int cc = n0 + wn * (BN / 4) + nf * 16 + lr;
#pragma unroll
      for (int j = 0; j < 4; ++j) {
        float v = acc[mf][nf][j];
        if (OUTF32)
          ((float*)Cout)[(size_t)(r + j) * N + cc] = v;
        else
          ((u16*)Cout)[(size_t)(r + j) * N + cc] = f2b(v);
      }
    }
  }
}

// ---------------- RoPE + permute [B][S][RS-cols] -> [B][H][S][D] ----------------
__global__ __launch_bounds__(256) void k_rope_perm(const u16* __restrict__ src,
                                                   u16* __restrict__ dst,
                                                   const float* __restrict__ cosb,
                                                   const float* __restrict__ sinb, int H,
                                                   int rs, int coloff) {
  const int row = blockIdx.x * 4 + (threadIdx.x >> 6);
  const int lane = threadIdx.x & 63;
  const int s = row & (S_ - 1);
  const int h = (row >> 11) % H;
  const int b = row / (S_ * H);
  const u16* sp = src + ((size_t)b * S_ + s) * rs + coloff + h * HD + lane * 2;
  const u32 u = *(const u32*)sp;
  const float f0 = b2f((u16)(u & 0xffffu));
  const float f1 = b2f((u16)(u >> 16));
  const float c = cosb[s * 64 + lane];
  const float sn = sinb[s * 64 + lane];
  const float r0 = f0 * c - f1 * sn;
  const float r1 = f0 * sn + f1 * c;
  const u32 o = (u32)f2b(r0) | ((u32)f2b(r1) << 16);
  *(u32*)(dst + (size_t)row * HD + lane * 2) = o;
}

// ---------------- V transpose: [B][S][rs cols @coloff] -> [B][NKV][HD][S] ----------------
__global__ __launch_bounds__(256) void k_transpose_v(const u16* __restrict__ vp,
                                                     u16* __restrict__ vt, int rs, int coloff) {
  __shared__ u16 tile[64][72];
  const int s0 = blockIdx.x * 64, d0 = blockIdx.y * 64;
  const int b = blockIdx.z >> 3, kvh = blockIdx.z & 7;
  const int tid = threadIdx.x;
  const int r = tid >> 3, c8 = (tid & 7) * 8;
#pragma unroll
  for (int i = 0; i < 2; ++i) {
    const int sl = r + 32 * i;
    *(u16x8*)&tile[sl][c8] =
        *(const u16x8*)&vp[((size_t)b * S_ + s0 + sl) * rs + coloff + kvh * HD + d0 + c8];
  }
  __syncthreads();
#pragma unroll
  for (int i = 0; i < 2; ++i) {
    const int dl = r + 32 * i;
    u16x8 o;
#pragma unroll
    for (int j = 0; j < 8; ++j) o[j] = tile[c8 + j][dl];
    *(u16x8*)&vt[(((size_t)b * NKV + kvh) * HD + d0 + dl) * S_ + s0 + c8] = o;
  }
}

// ---------------- Flash attention, causal, GQA rep=4, QB=128 / 8 waves ----------------
// LDS exactly 80KB -> 2 blocks/CU. K/V XOR-swizzled both sides; Ps de-padded but
// chunk-XOR-swizzled (read row=lr -> 8 distinct 16B slots, conflict-free).
__global__ __launch_bounds__(512, 4) void k_attn(const u16* __restrict__ Qg,
                                                 const u16* __restrict__ Kg,
                                                 const u16* __restrict__ Vtg,
                                                 u16* __restrict__ Og) {
  __shared__ __align__(16) u16 Ks[2][64 * 128];  // 2 x 16KB, rows 256B
  __shared__ __align__(16) u16 Vs[2][128 * 64];  // 2 x 16KB, rows 128B
  __shared__ u16 Ps[8][16][64];                  // 16KB, per-wave private, chunk-swizzled
  const int bid = blockIdx.x;
  const int xcd = bid & 7, slot = bid >> 3;     // grid 1024: 8 xcd x 128
  const int g = xcd * 2 + (slot >> 6);          // (b,kvh) group 0..15
  const int r_ = slot & 63;
  const int hq = r_ & 3;
  const int qt = 15 - (r_ >> 2);                // longest blocks first
  const int b = g >> 3, kvh = g & 7, h = kvh * 4 + hq;
  const int tid = threadIdx.x, wid = tid >> 6, lane = tid & 63;
  const int lr = lane & 15, lg = lane >> 4;
  const int q0 = qt * 128;
  const u16* qp = Qg + (((size_t)b * NH + h) * S_ + q0 + wid * 16 + lr) * HD + lg * 8;
  bf16x8 qf[4];
#pragma unroll
  for (int ks = 0; ks < 4; ++ks) qf[ks] = *(const bf16x8*)(qp + ks * 32);
  f32x4 o[8] = {};
  float mrun[4], lrun[4];
#pragma unroll
  for (int j = 0; j < 4; ++j) { mrun[j] = -1e30f; lrun[j] = 0.f; }
  const u16* kb2 = Kg + ((size_t)b * NKV + kvh) * (size_t)S_ * HD;
  const u16* vb2 = Vtg + ((size_t)b * NKV + kvh) * (size_t)HD * S_;

  // 4 block-wide loads per tile: K 2x32 rows (256B), V 2x64 rows (128B)
#define STAGE_KV(BUF, T)                                                               \
  {                                                                                    \
    _Pragma("unroll") for (int i = 0; i < 2; ++i) {                                    \
      const int kr = i * 32 + wid * 4 + lg;                                            \
      gload_lds16(kb2 + (size_t)((T) * 64 + kr) * HD + ((lane & 15) ^ (kr & 7)) * 8,   \
                  &Ks[BUF][(i * 32 + wid * 4) * 128]);                                 \
    }                                                                                  \
    _Pragma("unroll") for (int i = 0; i < 2; ++i) {                                    \
      const int dr = i * 64 + wid * 8 + (lane >> 3);                                   \
      gload_lds16(vb2 + (size_t)dr * S_ + (T) * 64 + ((lane & 7) ^ (dr & 7)) * 8,      \
                  &Vs[BUF][(i * 64 + wid * 8) * 64]);                                  \
    }                                                                                  \
  }

  const int nt = 2 * qt + 2;
  STAGE_KV(0, 0);
  asm volatile("s_waitcnt vmcnt(0)" ::: "memory");
  __builtin_amdgcn_sched_barrier(0);
  __builtin_amdgcn_s_barrier();
  __builtin_amdgcn_sched_barrier(0);
  int cur = 0;
  for (int t = 0; t < nt; ++t) {
    if (t < nt - 1) STAGE_KV(cur ^ 1, t + 1);
    __builtin_amdgcn_sched_barrier(0);
    const char* KsB = (const char*)&Ks[cur][0];
    const char* VsB = (const char*)&Vs[cur][0];
    f32x4 s[4] = {};
#pragma unroll
    for (int ks = 0; ks < 4; ++ks) {
      bf16x8 kf4[4];
#pragma unroll
      for (int n = 0; n < 4; ++n) {
        const int rr = n * 16 + lr;
        kf4[n] = *(const bf16x8*)(KsB + rr * 256 + ((ks * 64 + lg * 16) ^ ((rr & 7) << 4)));
      }
#pragma unroll
      for (int n = 0; n < 4; ++n)
        s[n] = __builtin_amdgcn_mfma_f32_16x16x32_bf16(qf[ks], kf4[n], s[n], 0, 0, 0);
    }
    const float scale = 0.08838834764831845f;
    float pm[4];
#pragma unroll
    for (int j = 0; j < 4; ++j) pm[j] = -1e30f;
    const bool diag = (t * 64 + 63 > q0 + wid * 16);
#pragma unroll
    for (int n = 0; n < 4; ++n)
#pragma unroll
      for (int j = 0; j < 4; ++j) {
        float v = s[n][j] * scale;
        if (diag && (t * 64 + n * 16 + lr > q0 + wid * 16 + lg * 4 + j)) v = -1e30f;
        s[n][j] = v;
        pm[j] = fmaxf(pm[j], v);
      }
#pragma unroll
    for (int off = 1; off < 16; off <<= 1)
#pragma unroll
      for (int j = 0; j < 4; ++j) pm[j] = fmaxf(pm[j], __shfl_xor(pm[j], off));
    float al[4];
#pragma unroll
    for (int j = 0; j < 4; ++j) {
      const float mt = fmaxf(mrun[j], pm[j]);
      al[j] = __expf(mrun[j] - mt);
      mrun[j] = mt;
    }
    float ls[4] = {0.f, 0.f, 0.f, 0.f};
#pragma unroll
    for (int n = 0; n < 4; ++n)
#pragma unroll
      for (int j = 0; j < 4; ++j) {
        const float p = __expf(s[n][j] - mrun[j]);
        ls[j] += p;
        const int prow = lg * 4 + j;
        Ps[wid][prow][(((n * 2 + (lr >> 3)) ^ (prow & 7)) << 3) + (lr & 7)] = f2b(p);
      }
#pragma unroll
    for (int off = 1; off < 16; off <<= 1)
#pragma unroll
      for (int j = 0; j < 4; ++j) ls[j] += __shfl_xor(ls[j], off);
#pragma unroll
    for (int j = 0; j < 4; ++j) lrun[j] = lrun[j] * al[j] + ls[j];
#pragma unroll
    for (int c = 0; c < 8; ++c)
#pragma unroll
      for (int j = 0; j < 4; ++j) o[c][j] *= al[j];
    asm volatile("s_waitcnt lgkmcnt(0)" ::: "memory");
    __builtin_amdgcn_sched_barrier(0);
#pragma unroll
    for (int ks = 0; ks < 2; ++ks) {
      bf16x8 af = *(const bf16x8*)&Ps[wid][lr][((ks * 4 + lg) ^ (lr & 7)) * 8];
#pragma unroll
      for (int c = 0; c < 8; ++c) {
        const int rv = c * 16 + lr;
        bf16x8 vf = *(const bf16x8*)(VsB + rv * 128 + ((ks * 64 + lg * 16) ^ ((rv & 7) << 4)));
        o[c] = __builtin_amdgcn_mfma_f32_16x16x32_bf16(af, vf, o[c], 0, 0, 0);
      }
    }
    asm volatile("s_waitcnt vmcnt(0)" ::: "memory");
    __builtin_amdgcn_sched_barrier(0);
    __builtin_amdgcn_s_barrier();
    __builtin_amdgcn_sched_barrier(0);
    cur ^= 1;
  }
#undef STAGE_KV
#pragma unroll
  for (int c = 0; c < 8; ++c)
#pragma unroll
    for (int j = 0; j < 4; ++j) {
      const int srow = q0 + wid * 16 + lg * 4 + j;
      const float v = o[c][j] / lrun[j];
      Og[((size_t)b * S_ + srow) * (NH * HD) + h * HD + c * 16 + lr] = f2b(v);
    }
}

extern "C" void kernel_launch(void* const* d_in, const int* in_sizes, int n_in,
                              void* d_out, int out_size, void* d_ws, size_t ws_size,
                              hipStream_t stream) {
  const float* x = (const float*)d_in[0];
  const float* fc = (const float*)d_in[1];
  const float* fs = (const float*)d_in[2];
  // d_in[3] positions (identity), d_in[4] mask (pure causal: WINDOW>=SEQ) -- analytic
  const float* wq = (const float*)d_in[5];
  const float* wk = (const float*)d_in[6];
  const float* wv = (const float*)d_in[7];
  const float* wo = (const float*)d_in[8];
  char* ws = (char*)d_ws;
  const size_t MB = 1024 * 1024;
  u16* xb = (u16*)(ws);                  // 32 MB  [4096][4096]
  u16* wqkvb = (u16*)(ws + 32 * MB);     // 48 MB  [6144][4096]
  u16* wkb = wqkvb + (size_t)4096 * 4096;
  u16* wvb = wqkvb + (size_t)5120 * 4096;
  u16* wob = (u16*)(ws + 80 * MB);       // 32 MB
  u16* qkvp = (u16*)(ws + 112 * MB);     // 48 MB  [B*S=4096][6144]
  // liveness reuse:
  u16* Q = xb;                           // [B][NH][S][HD] (xb free after qkv gemm)
  u16* Kr = (u16*)(ws + 32 * MB);        // 8 MB
  u16* Vt = (u16*)(ws + 40 * MB);        // 8 MB
  u16* attn = (u16*)(ws + 48 * MB);      // 32 MB
  float* out = (float*)d_out;

  k_f32_to_bf16<<<16384, 256, 0, stream>>>(x, xb, 4194304);
  k_f32_to_bf16<<<16384, 256, 0, stream>>>(wq, wqkvb, 4194304);
  k_f32_to_bf16<<<4096, 256, 0, stream>>>(wk, wkb, 1048576);
  k_f32_to_bf16<<<4096, 256, 0, stream>>>(wv, wvb, 1048576);
  k_f32_to_bf16<<<16384, 256, 0, stream>>>(wo, wob, 4194304);

  // fused QKV projection: 16x32 tiles of 256x192 -> 512 blocks = 2 exact rounds
  k_gemm256<192, NQKV, 4096, 0, 16, 32, 8, 8><<<512, 512, 0, stream>>>(xb, wqkvb, qkvp);

  k_rope_perm<<<32768, 256, 0, stream>>>(qkvp, Q, fc, fs, NH, NQKV, 0);
  k_rope_perm<<<8192, 256, 0, stream>>>(qkvp, Kr, fc, fs, NKV, NQKV, 4096);
  k_transpose_v<<<dim3(32, 2, 16), 256, 0, stream>>>(qkvp, Vt, NQKV, 5120);

  k_attn<<<1024, 512, 0, stream>>>(Q, Kr, Vt, attn);

  // O projection: 16x16 tiles of 256^2, XCD chunks 8x4 -> 256 blocks = 1 round
  k_gemm256<256, 4096, 4096, 1, 16, 16, 8, 4><<<256, 512, 0, stream>>>(attn, wob, out);
}

// Round 7
// 515.977 us; speedup vs baseline: 2.8288x; 1.0338x over previous
//
#include <hip/hip_runtime.h>
#include <hip/hip_bf16.h>

typedef unsigned short u16;
typedef unsigned int u32;
typedef __bf16 bf16x8 __attribute__((ext_vector_type(8)));
typedef float f32x4 __attribute__((ext_vector_type(4)));
typedef u16 u16x8 __attribute__((ext_vector_type(8)));

#define B_ 2
#define S_ 2048
#define NH 32
#define NKV 8
#define HD 128
#define DIM_ 4096
#define NQKV 6144  // fused projection width: 4096 Q + 1024 K + 1024 V

__device__ inline u16 f2b(float f) {
  u32 u = __builtin_bit_cast(u32, f);
  u = (u + 0x7fffu + ((u >> 16) & 1u)) >> 16;
  return (u16)u;
}
__device__ inline float b2f(u16 b) {
  u32 u = ((u32)b) << 16;
  return __builtin_bit_cast(float, u);
}

__device__ inline void gload_lds16(const u16* g, u16* l) {
  __builtin_amdgcn_global_load_lds((__attribute__((address_space(1))) void*)g,
                                   (__attribute__((address_space(3))) void*)l, 16, 0, 0);
}

// ---------------- merged f32 -> bf16 cast (all 5 tensors, one launch) ----------------
// segments (float4 units): x 4194304 | wq 4194304 | wk 1048576 | wv 1048576 | wo 4194304
__global__ __launch_bounds__(256) void k_cast_all(const float* __restrict__ x,
                                                  const float* __restrict__ wq,
                                                  const float* __restrict__ wk,
                                                  const float* __restrict__ wv,
                                                  const float* __restrict__ wo,
                                                  u16* __restrict__ xb,
                                                  u16* __restrict__ wqkvb,
                                                  u16* __restrict__ wob) {
  int i = blockIdx.x * 256 + threadIdx.x;
  const float* s;
  u16* d;
  int j;
  if (i < 4194304) { s = x; d = xb; j = i; }
  else if (i < 8388608) { s = wq; d = wqkvb; j = i - 4194304; }
  else if (i < 9437184) { s = wk; d = wqkvb + (size_t)4096 * 4096; j = i - 8388608; }
  else if (i < 10485760) { s = wv; d = wqkvb + (size_t)5120 * 4096; j = i - 9437184; }
  else { s = wo; d = wob; j = i - 10485760; }
  const float4 v = ((const float4*)s)[j];
  u32 lo = (u32)f2b(v.x) | ((u32)f2b(v.y) << 16);
  u32 hi = (u32)f2b(v.z) | ((u32)f2b(v.w) << 16);
  ((u32*)d)[(size_t)j * 2] = lo;
  ((u32*)d)[(size_t)j * 2 + 1] = hi;
}

#define BARRIER_()                      \
  __builtin_amdgcn_sched_barrier(0);    \
  __builtin_amdgcn_s_barrier();         \
  __builtin_amdgcn_sched_barrier(0)

// ================= 256x192 nf-split 3-phase GEMM: C = A*B^T (bf16 out) =================
// 8 waves (2m x 4n). Per K-tile: 3 phases, one B-group each, 16 MFMA/phase
// (8 m-frags x 1 nf x 2 ks). A-frags af[8][2] read once at p0, held 3 phases.
// Column map: cc = n0 + p*64 + wn*16 + lr  (phase p touches only B-group 4+p).
// Stage next tile 7 loads as p0:{A0,A2,A1} p1:{A3,B4} p2:{B5,B6}; counted waits:
// p0-end vmcnt(4) [B5 lands], p1-end vmcnt(5) [B6 lands], boundary vmcnt(2)
// [A0,A2,A1,A3,B4 land; B5',B6' stay in flight].
template <int N, int K, int MT, int NT, int CM, int CN>
__global__ __launch_bounds__(512, 2) void k_gemm192nf(const u16* __restrict__ A,
                                                      const u16* __restrict__ Bm,
                                                      u16* __restrict__ Cout) {
  __shared__ __align__(16) u16 lds[2][7][64 * 64];  // 112KB
  const int bid = blockIdx.x;
  const int xcd = bid & 7, slot = bid >> 3;
  constexpr int XM = MT / CM;
  const int xm = xcd % XM, xn = xcd / XM;
  const int m0 = (xm * CM + slot % CM) * 256;
  const int n0 = (xn * CN + slot / CM) * 192;
  const int tid = threadIdx.x, w = tid >> 6, lane = tid & 63;
  const int wm = w >> 2, wn = w & 3;
  const int lr = lane & 15, lg = lane >> 4;
  const int lrow8 = lane >> 3;
  const int gcol = ((lane & 7) ^ lrow8) * 8;  // pre-swizzled source k-col (u16)
  f32x4 acc[8][3] = {};
  const u16* gsrc[7];
#pragma unroll
  for (int g = 0; g < 4; ++g) gsrc[g] = A + (size_t)(m0 + g * 64) * K;
#pragma unroll
  for (int g = 0; g < 3; ++g) gsrc[4 + g] = Bm + (size_t)(n0 + g * 64) * K;

#define SG(DST, G, KN) \
  gload_lds16(gsrc[G] + (size_t)(w * 8 + lrow8) * K + (KN) + gcol, &lds[DST][G][w * 512])

#define TILE3(BB, HS, KN, LAST)                                                           \
  {                                                                                       \
    bf16x8 af[8][2];                                                                      \
    _Pragma("unroll") for (int p = 0; p < 3; ++p) {                                       \
      if (p == 0) {                                                                       \
        _Pragma("unroll") for (int f = 0; f < 8; ++f)                                     \
          _Pragma("unroll") for (int ks = 0; ks < 2; ++ks)                                \
            af[f][ks] = *(const bf16x8*)&lds[BB][wm * 2 + (f >> 2)]                       \
                [((f & 3) * 16 + lr) * 64 + ((ks * 4 + lg) ^ (lr & 7)) * 8];              \
      }                                                                                   \
      bf16x8 bfr[2];                                                                      \
      _Pragma("unroll") for (int ks = 0; ks < 2; ++ks)                                    \
        bfr[ks] = *(const bf16x8*)&lds[BB][4 + p]                                         \
            [(wn * 16 + lr) * 64 + ((ks * 4 + lg) ^ (lr & 7)) * 8];                       \
      if (HS) {                                                                           \
        if (p == 0) { SG(BB ^ 1, 0, KN); SG(BB ^ 1, 2, KN); SG(BB ^ 1, 1, KN); }          \
        if (p == 1) { SG(BB ^ 1, 3, KN); SG(BB ^ 1, 4, KN); }                             \
        if (p == 2) { SG(BB ^ 1, 5, KN); SG(BB ^ 1, 6, KN); }                             \
      }                                                                                   \
      BARRIER_();                                                                         \
      __builtin_amdgcn_s_setprio(1);                                                      \
      _Pragma("unroll") for (int f = 0; f < 8; ++f)                                       \
        _Pragma("unroll") for (int ks = 0; ks < 2; ++ks)                                  \
          acc[f][p] = __builtin_amdgcn_mfma_f32_16x16x32_bf16(af[f][ks], bfr[ks],         \
                                                              acc[f][p], 0, 0, 0);       \
      __builtin_amdgcn_s_setprio(0);                                                      \
      if (p == 0 && HS) asm volatile("s_waitcnt vmcnt(4)" ::: "memory");                  \
      if (p == 1 && HS) asm volatile("s_waitcnt vmcnt(5)" ::: "memory");                  \
      if (p == 2 && LAST == 2) asm volatile("s_waitcnt vmcnt(2)" ::: "memory");           \
      if (p == 2 && LAST == 9) asm volatile("s_waitcnt vmcnt(0)" ::: "memory");           \
      BARRIER_();                                                                         \
    }                                                                                     \
  }

  // prologue: stage tile 0 -> buf0, full drain
#pragma unroll
  for (int g = 0; g < 7; ++g) SG(0, g, 0);
  asm volatile("s_waitcnt vmcnt(0)" ::: "memory");
  BARRIER_();

  for (int tt = 0; tt < (K / 64) - 2; tt += 2) {
    TILE3(0, 1, (tt + 1) * 64, 2);
    TILE3(1, 1, (tt + 2) * 64, 2);
  }
  TILE3(0, 1, (K / 64 - 1) * 64, 9);
  TILE3(1, 0, 0, 0);
#undef TILE3
#undef SG

#pragma unroll
  for (int mf = 0; mf < 8; ++mf) {
    const int r = m0 + wm * 128 + mf * 16 + lg * 4;
#pragma unroll
    for (int p = 0; p < 3; ++p) {
      const int cc = n0 + p * 64 + wn * 16 + lr;
#pragma unroll
      for (int j = 0; j < 4; ++j)
        Cout[(size_t)(r + j) * N + cc] = f2b(acc[mf][p][j]);
    }
  }
}

// ================= 256x256 4-phase GEMM (O-projection, f32 out) =================
template <int BN, int N, int K, int OUTF32, int MT, int NT, int CM, int CN>
__global__ __launch_bounds__(512, 2) void k_gemm256(const u16* __restrict__ A,
                                                    const u16* __restrict__ Bm,
                                                    void* __restrict__ Cout) {
  constexpr int GB = BN / 64;
  __shared__ __align__(16) u16 lds[2][4 + GB][64 * 64];
  const int bid = blockIdx.x;
  const int xcd = bid & 7, slot = bid >> 3;
  constexpr int XM = MT / CM;
  const int xm = xcd % XM, xn = xcd / XM;
  const int m0 = (xm * CM + slot % CM) * 256;
  const int n0 = (xn * CN + slot / CM) * BN;
  const int tid = threadIdx.x, w = tid >> 6, lane = tid & 63;
  const int wm = w >> 2, wn = w & 3;
  const int lr = lane & 15, lg = lane >> 4;
  const int lrow8 = lane >> 3;
  const int gcol = ((lane & 7) ^ lrow8) * 8;
  f32x4 acc[8][GB] = {};
  const u16* gsrc[4 + GB];
#pragma unroll
  for (int g = 0; g < 4; ++g) gsrc[g] = A + (size_t)(m0 + g * 64) * K;
#pragma unroll
  for (int g = 0; g < GB; ++g) gsrc[4 + g] = Bm + (size_t)(n0 + g * 64) * K;

#define SG(DST, G, KN) \
  gload_lds16(gsrc[G] + (size_t)(w * 8 + lrow8) * K + (KN) + gcol, &lds[DST][G][w * 512])

#define TILE(BB, HS, KN, LASTVM)                                                          \
  {                                                                                       \
    const u16* Lb = &lds[BB][0][0];                                                       \
    bf16x8 bfr[GB][2];                                                                    \
    _Pragma("unroll") for (int p = 0; p < 4; ++p) {                                       \
      if (HS) {                                                                           \
        if (p == 0) { SG(BB ^ 1, 4, KN); SG(BB ^ 1, 5, KN); }                             \
        if (p == 1) { SG(BB ^ 1, 6, KN); SG(BB ^ 1, 7, KN); }                             \
        if (p == 2) { SG(BB ^ 1, 0, KN); SG(BB ^ 1, 2, KN); }                             \
        if (p == 3) { SG(BB ^ 1, 1, KN); SG(BB ^ 1, 3, KN); }                             \
      }                                                                                   \
      bf16x8 af[2][2];                                                                    \
      _Pragma("unroll") for (int mi = 0; mi < 2; ++mi)                                    \
        _Pragma("unroll") for (int ks = 0; ks < 2; ++ks)                                  \
          af[mi][ks] = *(const bf16x8*)&Lb[(size_t)(wm * 2 + ((p * 2 + mi) >> 2)) * 4096 +\
              (((p * 2 + mi) & 3) * 16 + lr) * 64 + ((ks * 4 + lg) ^ (lr & 7)) * 8];      \
      if (p == 0) {                                                                       \
        _Pragma("unroll") for (int nf = 0; nf < GB; ++nf) {                               \
          const int rowB = wn * (BN / 4) + nf * 16 + lr;                                  \
          _Pragma("unroll") for (int ks = 0; ks < 2; ++ks)                                \
            bfr[nf][ks] = *(const bf16x8*)&Lb[(size_t)(4 + (rowB >> 6)) * 4096 +          \
                (rowB & 63) * 64 + ((ks * 4 + lg) ^ (lr & 7)) * 8];                       \
        }                                                                                 \
      }                                                                                   \
      BARRIER_();                                                                         \
      __builtin_amdgcn_s_setprio(1);                                                      \
      _Pragma("unroll") for (int mi = 0; mi < 2; ++mi)                                    \
        _Pragma("unroll") for (int nf = 0; nf < GB; ++nf)                                 \
          _Pragma("unroll") for (int ks = 0; ks < 2; ++ks)                                \
            acc[p * 2 + mi][nf] = __builtin_amdgcn_mfma_f32_16x16x32_bf16(                \
                af[mi][ks], bfr[nf][ks], acc[p * 2 + mi][nf], 0, 0, 0);                   \
      __builtin_amdgcn_s_setprio(0);                                                      \
      if (p == 1 && HS) asm volatile("s_waitcnt vmcnt(4)" ::: "memory");                  \
      if (p == 3 && LASTVM == 2) asm volatile("s_waitcnt vmcnt(2)" ::: "memory");         \
      if (p == 3 && LASTVM == 9) asm volatile("s_waitcnt vmcnt(0)" ::: "memory");         \
      BARRIER_();                                                                         \
    }                                                                                     \
  }

#pragma unroll
  for (int g = 0; g < 4 + GB; ++g) SG(0, g, 0);
  asm volatile("s_waitcnt vmcnt(0)" ::: "memory");
  BARRIER_();

  for (int tt = 0; tt < (K / 64) - 2; tt += 2) {
    TILE(0, 1, (tt + 1) * 64, 2);
    TILE(1, 1, (tt + 2) * 64, 2);
  }
  TILE(0, 1, (K / 64 - 1) * 64, 9);
  TILE(1, 0, 0, 0);
#undef TILE
#undef SG

#pragma unroll
  for (int mf = 0; mf < 8; ++mf) {
    const int r = m0 + wm * 128 + mf * 16 + lg * 4;
#pragma unroll
    for (int nf = 0; nf < GB; ++nf) {
      const int cc = n0 + wn * (BN / 4) + nf * 16 + lr;
#pragma unroll
      for (int j = 0; j < 4; ++j) {
        float v = acc[mf][nf][j];
        if (OUTF32)
          ((float*)Cout)[(size_t)(r + j) * N + cc] = v;
        else
          ((u16*)Cout)[(size_t)(r + j) * N + cc] = f2b(v);
      }
    }
  }
}

// ---------- merged RoPE(Q) + RoPE(K) + V-transpose, one launch ----------
// blocks [0,32768): rope Q | [32768,40960): rope K | [40960,41984): V transpose
__global__ __launch_bounds__(256) void k_rt(const u16* __restrict__ qkvp,
                                            u16* __restrict__ Q, u16* __restrict__ Kr,
                                            u16* __restrict__ Vt,
                                            const float* __restrict__ cosb,
                                            const float* __restrict__ sinb) {
  __shared__ u16 tile[64][72];
  const int bid = blockIdx.x;
  const int tid = threadIdx.x;
  if (bid < 40960) {
    const int isQ = bid < 32768;
    const int H = isQ ? NH : NKV;
    const int coloff = isQ ? 0 : 4096;
    u16* dst = isQ ? Q : Kr;
    const int row = (isQ ? bid : bid - 32768) * 4 + (tid >> 6);
    const int lane = tid & 63;
    const int s = row & (S_ - 1);
    const int h = (row >> 11) % H;
    const int b = row / (S_ * H);
    const u16* sp = qkvp + ((size_t)b * S_ + s) * NQKV + coloff + h * HD + lane * 2;
    const u32 u = *(const u32*)sp;
    const float f0 = b2f((u16)(u & 0xffffu));
    const float f1 = b2f((u16)(u >> 16));
    const float c = cosb[s * 64 + lane];
    const float sn = sinb[s * 64 + lane];
    const float r0 = f0 * c - f1 * sn;
    const float r1 = f0 * sn + f1 * c;
    const u32 o = (u32)f2b(r0) | ((u32)f2b(r1) << 16);
    *(u32*)(dst + (size_t)row * HD + lane * 2) = o;
  } else {
    const int t = bid - 40960;
    const int s0 = (t & 31) * 64, d0 = ((t >> 5) & 1) * 64;
    const int z = t >> 6;
    const int b = z >> 3, kvh = z & 7;
    const int r = tid >> 3, c8 = (tid & 7) * 8;
#pragma unroll
    for (int i = 0; i < 2; ++i) {
      const int sl = r + 32 * i;
      *(u16x8*)&tile[sl][c8] =
          *(const u16x8*)&qkvp[((size_t)b * S_ + s0 + sl) * NQKV + 5120 + kvh * HD + d0 + c8];
    }
    __syncthreads();
#pragma unroll
    for (int i = 0; i < 2; ++i) {
      const int dl = r + 32 * i;
      u16x8 o;
#pragma unroll
      for (int j = 0; j < 8; ++j) o[j] = tile[c8 + j][dl];
      *(u16x8*)&Vt[(((size_t)b * NKV + kvh) * HD + d0 + dl) * S_ + s0 + c8] = o;
    }
  }
}

// ---------------- Flash attention, causal, GQA rep=4, QB=128 / 8 waves ----------------
__global__ __launch_bounds__(512, 4) void k_attn(const u16* __restrict__ Qg,
                                                 const u16* __restrict__ Kg,
                                                 const u16* __restrict__ Vtg,
                                                 u16* __restrict__ Og) {
  __shared__ __align__(16) u16 Ks[2][64 * 128];  // 2 x 16KB, rows 256B
  __shared__ __align__(16) u16 Vs[2][128 * 64];  // 2 x 16KB, rows 128B
  __shared__ u16 Ps[8][16][64];                  // 16KB, per-wave private, chunk-swizzled
  const int bid = blockIdx.x;
  const int xcd = bid & 7, slot = bid >> 3;     // grid 1024: 8 xcd x 128
  const int g = xcd * 2 + (slot >> 6);          // (b,kvh) group 0..15
  const int r_ = slot & 63;
  const int hq = r_ & 3;
  const int qt = 15 - (r_ >> 2);                // longest blocks first
  const int b = g >> 3, kvh = g & 7, h = kvh * 4 + hq;
  const int tid = threadIdx.x, wid = tid >> 6, lane = tid & 63;
  const int lr = lane & 15, lg = lane >> 4;
  const int q0 = qt * 128;
  const u16* qp = Qg + (((size_t)b * NH + h) * S_ + q0 + wid * 16 + lr) * HD + lg * 8;
  bf16x8 qf[4];
#pragma unroll
  for (int ks = 0; ks < 4; ++ks) qf[ks] = *(const bf16x8*)(qp + ks * 32);
  f32x4 o[8] = {};
  float mrun[4], lrun[4];
#pragma unroll
  for (int j = 0; j < 4; ++j) { mrun[j] = -1e30f; lrun[j] = 0.f; }
  const u16* kb2 = Kg + ((size_t)b * NKV + kvh) * (size_t)S_ * HD;
  const u16* vb2 = Vtg + ((size_t)b * NKV + kvh) * (size_t)HD * S_;

#define STAGE_KV(BUF, T)                                                               \
  {                                                                                    \
    _Pragma("unroll") for (int i = 0; i < 2; ++i) {                                    \
      const int kr = i * 32 + wid * 4 + lg;                                            \
      gload_lds16(kb2 + (size_t)((T) * 64 + kr) * HD + ((lane & 15) ^ (kr & 7)) * 8,   \
                  &Ks[BUF][(i * 32 + wid * 4) * 128]);                                 \
    }                                                                                  \
    _Pragma("unroll") for (int i = 0; i < 2; ++i) {                                    \
      const int dr = i * 64 + wid * 8 + (lane >> 3);                                   \
      gload_lds16(vb2 + (size_t)dr * S_ + (T) * 64 + ((lane & 7) ^ (dr & 7)) * 8,      \
                  &Vs[BUF][(i * 64 + wid * 8) * 64]);                                  \
    }                                                                                  \
  }

  const int nt = 2 * qt + 2;
  STAGE_KV(0, 0);
  asm volatile("s_waitcnt vmcnt(0)" ::: "memory");
  BARRIER_();
  int cur = 0;
  for (int t = 0; t < nt; ++t) {
    if (t < nt - 1) STAGE_KV(cur ^ 1, t + 1);
    __builtin_amdgcn_sched_barrier(0);
    const char* KsB = (const char*)&Ks[cur][0];
    const char* VsB = (const char*)&Vs[cur][0];
    f32x4 s[4] = {};
#pragma unroll
    for (int ks = 0; ks < 4; ++ks) {
      bf16x8 kf4[4];
#pragma unroll
      for (int n = 0; n < 4; ++n) {
        const int rr = n * 16 + lr;
        kf4[n] = *(const bf16x8*)(KsB + rr * 256 + ((ks * 64 + lg * 16) ^ ((rr & 7) << 4)));
      }
#pragma unroll
      for (int n = 0; n < 4; ++n)
        s[n] = __builtin_amdgcn_mfma_f32_16x16x32_bf16(qf[ks], kf4[n], s[n], 0, 0, 0);
    }
    const float scale = 0.08838834764831845f;
    float pm[4];
#pragma unroll
    for (int j = 0; j < 4; ++j) pm[j] = -1e30f;
    const bool diag = (t * 64 + 63 > q0 + wid * 16);
#pragma unroll
    for (int n = 0; n < 4; ++n)
#pragma unroll
      for (int j = 0; j < 4; ++j) {
        float v = s[n][j] * scale;
        if (diag && (t * 64 + n * 16 + lr > q0 + wid * 16 + lg * 4 + j)) v = -1e30f;
        s[n][j] = v;
        pm[j] = fmaxf(pm[j], v);
      }
#pragma unroll
    for (int off = 1; off < 16; off <<= 1)
#pragma unroll
      for (int j = 0; j < 4; ++j) pm[j] = fmaxf(pm[j], __shfl_xor(pm[j], off));
    float al[4];
#pragma unroll
    for (int j = 0; j < 4; ++j) {
      const float mt = fmaxf(mrun[j], pm[j]);
      al[j] = __expf(mrun[j] - mt);
      mrun[j] = mt;
    }
    float ls[4] = {0.f, 0.f, 0.f, 0.f};
#pragma unroll
    for (int n = 0; n < 4; ++n)
#pragma unroll
      for (int j = 0; j < 4; ++j) {
        const float p = __expf(s[n][j] - mrun[j]);
        ls[j] += p;
        const int prow = lg * 4 + j;
        Ps[wid][prow][(((n * 2 + (lr >> 3)) ^ (prow & 7)) << 3) + (lr & 7)] = f2b(p);
      }
#pragma unroll
    for (int off = 1; off < 16; off <<= 1)
#pragma unroll
      for (int j = 0; j < 4; ++j) ls[j] += __shfl_xor(ls[j], off);
#pragma unroll
    for (int j = 0; j < 4; ++j) lrun[j] = lrun[j] * al[j] + ls[j];
#pragma unroll
    for (int c = 0; c < 8; ++c)
#pragma unroll
      for (int j = 0; j < 4; ++j) o[c][j] *= al[j];
    asm volatile("s_waitcnt lgkmcnt(0)" ::: "memory");
    __builtin_amdgcn_sched_barrier(0);
#pragma unroll
    for (int ks = 0; ks < 2; ++ks) {
      bf16x8 af = *(const bf16x8*)&Ps[wid][lr][((ks * 4 + lg) ^ (lr & 7)) * 8];
#pragma unroll
      for (int c = 0; c < 8; ++c) {
        const int rv = c * 16 + lr;
        bf16x8 vf = *(const bf16x8*)(VsB + rv * 128 + ((ks * 64 + lg * 16) ^ ((rv & 7) << 4)));
        o[c] = __builtin_amdgcn_mfma_f32_16x16x32_bf16(af, vf, o[c], 0, 0, 0);
      }
    }
    asm volatile("s_waitcnt vmcnt(0)" ::: "memory");
    BARRIER_();
    cur ^= 1;
  }
#undef STAGE_KV
#pragma unroll
  for (int c = 0; c < 8; ++c)
#pragma unroll
    for (int j = 0; j < 4; ++j) {
      const int srow = q0 + wid * 16 + lg * 4 + j;
      const float v = o[c][j] / lrun[j];
      Og[((size_t)b * S_ + srow) * (NH * HD) + h * HD + c * 16 + lr] = f2b(v);
    }
}

extern "C" void kernel_launch(void* const* d_in, const int* in_sizes, int n_in,
                              void* d_out, int out_size, void* d_ws, size_t ws_size,
                              hipStream_t stream) {
  const float* x = (const float*)d_in[0];
  const float* fc = (const float*)d_in[1];
  const float* fs = (const float*)d_in[2];
  // d_in[3] positions (identity), d_in[4] mask (pure causal: WINDOW>=SEQ) -- analytic
  const float* wq = (const float*)d_in[5];
  const float* wk = (const float*)d_in[6];
  const float* wv = (const float*)d_in[7];
  const float* wo = (const float*)d_in[8];
  char* ws = (char*)d_ws;
  const size_t MB = 1024 * 1024;
  u16* xb = (u16*)(ws);                  // 32 MB  [4096][4096]
  u16* wqkvb = (u16*)(ws + 32 * MB);     // 48 MB  [6144][4096]
  u16* wob = (u16*)(ws + 80 * MB);       // 32 MB
  u16* qkvp = (u16*)(ws + 112 * MB);     // 48 MB  [B*S=4096][6144]
  // liveness reuse:
  u16* Q = xb;                           // [B][NH][S][HD] (xb free after qkv gemm)
  u16* Kr = (u16*)(ws + 32 * MB);        // 8 MB
  u16* Vt = (u16*)(ws + 40 * MB);        // 8 MB
  u16* attn = (u16*)(ws + 48 * MB);      // 32 MB
  float* out = (float*)d_out;

  // all 5 casts in one launch (14,680,064 float4s / 256)
  k_cast_all<<<57344, 256, 0, stream>>>(x, wq, wk, wv, wo, xb, wqkvb, wob);

  // fused QKV projection: 16x32 tiles of 256x192 (nf-split 3-phase), 2 exact rounds
  k_gemm192nf<NQKV, 4096, 16, 32, 8, 8><<<512, 512, 0, stream>>>(xb, wqkvb, qkvp);

  // RoPE Q + RoPE K + V transpose, one launch
  k_rt<<<41984, 256, 0, stream>>>(qkvp, Q, Kr, Vt, fc, fs);

  k_attn<<<1024, 512, 0, stream>>>(Q, Kr, Vt, attn);

  // O projection: 16x16 tiles of 256^2, XCD chunks 8x4 -> 256 blocks = 1 round
  k_gemm256<256, 4096, 4096, 1, 16, 16, 8, 4><<<256, 512, 0, stream>>>(attn, wob, out);
}